// Round 6
// baseline (758.369 us; speedup 1.0000x reference)
//
#include <hip/hip_runtime.h>
#include <hip/hip_bf16.h>

typedef short v8s __attribute__((ext_vector_type(8)));
typedef short v4s __attribute__((ext_vector_type(4)));
typedef float v4f __attribute__((ext_vector_type(4)));

#define B2ROWS 8224   /* 32*257 */
#define ROWS   16448  /* 64*257 */

// Fast exact-GELU: erf via Abramowitz-Stegun 7.1.26 (|err| <= 1.5e-7, far
// below bf16 ulp). ~14 VALU ops (rcp + v_exp + 5 FMA) vs libm erff.
__device__ __forceinline__ float fast_gelu(float z) {
  float u = z * 0.70710678118654752f;
  float a = fabsf(u);
  float t = __builtin_amdgcn_rcpf(1.0f + 0.3275911f * a);
  float p = t * (0.254829592f + t * (-0.284496736f + t * (1.421413741f +
            t * (-1.453152027f + t * 1.061405429f))));
  float e = __expf(-a * a);
  float erfa = 1.0f - p * e;
  float erfu = copysignf(erfa, u);
  return 0.5f * z * (1.0f + erfu);
}

// ---------------- weight prep: transpose fp32 (K x N) -> bf16 (N x K) ----------------
__global__ __launch_bounds__(256) void wprep(const float* __restrict__ W,
                                             __hip_bfloat16* __restrict__ Wt,
                                             int K, int N, int variant,
                                             const float* __restrict__ gw) {
  int k = blockIdx.x * 256 + threadIdx.x;
  int n = blockIdx.y;
  if (k >= K) return;
  float v = W[(size_t)k * N + n];
  if (variant == 1) {
    int h = k >> 6;  // head index
    float s = gw[0];
    if (h < 6 && n < 384) s += gw[1];
    if (h < 4 && n < 256) s += gw[2];
    v *= s;
  }
  Wt[(size_t)n * K + k] = __float2bfloat16(v);
}

__global__ void bias_prep(const float* __restrict__ bp, const float* __restrict__ b2,
                          const float* __restrict__ gw,
                          float* __restrict__ b_small, float* __restrict__ b2_small) {
  int c = blockIdx.x * 256 + threadIdx.x;
  if (c >= 768) return;
  float s = gw[0] + (c < 384 ? gw[1] : 0.f) + (c < 256 ? gw[2] : 0.f);
  b_small[c] = bp[c] * s;
  b2_small[c] = b2[c] * s;
}

// ---------------- LayerNorm: fp32 in -> bf16 out, one row per wave ----------------
__global__ __launch_bounds__(256) void ln_k(const float* __restrict__ X,
                                            __hip_bfloat16* __restrict__ out,
                                            const float* __restrict__ gl, const float* __restrict__ bl,
                                            const float* __restrict__ gs, const float* __restrict__ bs) {
  int wave = threadIdx.x >> 6, lane = threadIdx.x & 63;
  int row = blockIdx.x * 4 + wave;
  const float* g = (row < B2ROWS) ? gl : gs;
  const float* b = (row < B2ROWS) ? bl : bs;
  const float* xr = X + (size_t)row * 768;
  float v[12]; float s = 0.f, ss = 0.f;
#pragma unroll
  for (int i = 0; i < 12; i++) { v[i] = xr[lane + i * 64]; s += v[i]; ss += v[i] * v[i]; }
#pragma unroll
  for (int o = 32; o > 0; o >>= 1) { s += __shfl_xor(s, o, 64); ss += __shfl_xor(ss, o, 64); }
  float mean = s * (1.0f / 768.0f);
  float var = ss * (1.0f / 768.0f) - mean * mean;
  float rstd = rsqrtf(var + 1e-5f);
  __hip_bfloat16* orow = out + (size_t)row * 768;
#pragma unroll
  for (int i = 0; i < 12; i++) {
    int c = lane + i * 64;
    orow[c] = __float2bfloat16((v[i] - mean) * rstd * g[c] + b[c]);
  }
}

// ---------------- bf16 MFMA GEMM: C(MxN) = A(MxK) * Bt(NxK)^T, 128x128 tile ----------------
// v6: main loop unchanged (triple-buffered LDS, depth-2 prefetch, counted
// vmcnt(4), raw s_barrier; per-wave LDS-transpose epilogue; bijective XCD
// swizzle). NEW mode 6: merged large+small FC2 (grid y doubled): post-swizzle
// row-tile >= 65 selects the small branch (per-n0 A-select among
// aux2/aux1/aux3, bias=bias2, resid/out + B2ROWS rows), else the large branch
// (A, bias); then behaves as mode 2.
// mode 0: out bf16 = acc
// mode 1: out bf16 = scale*gelu(acc + bias) + (addin ? addin : 0)   (addin may alias out)
// mode 2: out fp32 = acc + bias + resid                             (resid may alias out)
// mode 4: merged small-FC2: A-select by n0 (<256 -> aux2, <384 -> aux1), then mode 2
// mode 5: merged proj pair (row-tile >= 65 -> small params), then mode 2
__global__ __launch_bounds__(256) void gemm_k(
    const __hip_bfloat16* __restrict__ A, int lda,
    const __hip_bfloat16* __restrict__ Bt, int ldb,
    int M, int K,
    const float* __restrict__ bias,
    const float* __restrict__ resid, int ldr,
    const float* __restrict__ gw, int gidx,
    const __hip_bfloat16* __restrict__ addin,
    void* __restrict__ out, int ldo,
    int mode,
    const __hip_bfloat16* __restrict__ aux1,
    const __hip_bfloat16* __restrict__ aux2,
    const float* __restrict__ bias2,
    const __hip_bfloat16* __restrict__ aux3) {
  __shared__ __attribute__((aligned(16))) short Asm[3][128 * 32];
  __shared__ __attribute__((aligned(16))) short Bsm[3][128 * 32];
  int tid = threadIdx.x;
  int lane = tid & 63;
  int wave = tid >> 6;
  int wm = wave >> 1, wn = wave & 1;
  int l16 = lane & 15, quad = lane >> 4;

  // ---- bijective XCD-chunked swizzle (m204) ----
  int gx = gridDim.x;
  int nwg = gx * gridDim.y;
  int bid = blockIdx.y * gx + blockIdx.x;
  int q8 = nwg >> 3, r8 = nwg & 7;
  int xcd = bid & 7, lid = bid >> 3;
  int nb = (xcd < r8 ? xcd * (q8 + 1) : r8 * (q8 + 1) + (xcd - r8) * q8) + lid;
  int m0 = (nb / gx) * 128, n0 = (nb % gx) * 128;

  int sw = (quad ^ ((l16 >> 1) & 3)) * 8;   // swizzled read chunk offset (shorts)

  // per-mode parameter selection
  const __hip_bfloat16* Ause = A;
  const __hip_bfloat16* Btuse = Bt;
  const float* bias_u = bias;
  const float* resid_u = resid;
  void* out_u = out;
  if (mode == 4) {
    if (n0 < 256) Ause = aux2;
    else if (n0 < 384) Ause = aux1;
    mode = 2;
  } else if (mode == 5) {
    if (m0 >= 8320) {                 // 65 * 128: second (small) half
      m0 -= 8320;
      Ause = A + (size_t)B2ROWS * lda;
      Btuse = aux1;
      bias_u = bias2;
      resid_u = resid + (size_t)B2ROWS * ldr;
      out_u = (void*)((float*)out + (size_t)B2ROWS * ldo);
    }
    mode = 2;
  } else if (mode == 6) {
    if (m0 >= 8320) {                 // small half
      m0 -= 8320;
      if (n0 < 256) Ause = aux2;
      else if (n0 < 384) Ause = aux1;
      else Ause = aux3;
      bias_u = bias2;
      resid_u = resid + (size_t)B2ROWS * ldr;
      out_u = (void*)((float*)out + (size_t)B2ROWS * ldo);
    }
    mode = 2;
  }

  // staging address components (per lane)
  int r4 = lane >> 2;                        // row within 16-row wave chunk
  int qs = (lane & 3) ^ ((r4 >> 1) & 3);     // swizzled SOURCE k-chunk

  const ushort* Au = (const ushort*)Ause;
  const ushort* Bu = (const ushort*)Btuse;

  const ushort* agp[2];
  const ushort* bgp[2];
  int lof[2];
#pragma unroll
  for (int it = 0; it < 2; it++) {
    int rbase = wave * 16 + it * 64;
    int gr = m0 + rbase + r4; if (gr > M - 1) gr = M - 1;
    agp[it] = Au + (size_t)gr * lda + qs * 8;
    int gn = n0 + rbase + r4;                // N always a multiple of 128
    bgp[it] = Bu + (size_t)gn * ldb + qs * 8;
    lof[it] = rbase * 32;
  }

  v4f acc[4][4];
#pragma unroll
  for (int i = 0; i < 4; i++)
#pragma unroll
    for (int j = 0; j < 4; j++) acc[i][j] = (v4f){0.f, 0.f, 0.f, 0.f};

  auto stage = [&](int buf, int ko) {
#pragma unroll
    for (int it = 0; it < 2; it++) {
      __builtin_amdgcn_global_load_lds(
          (const __attribute__((address_space(1))) uint32_t*)(uintptr_t)(const void*)(agp[it] + ko),
          (__attribute__((address_space(3))) uint32_t*)(uint32_t)(uintptr_t)(const void*)&Asm[buf][lof[it]],
          16, 0, 0);
      __builtin_amdgcn_global_load_lds(
          (const __attribute__((address_space(1))) uint32_t*)(uintptr_t)(const void*)(bgp[it] + ko),
          (__attribute__((address_space(3))) uint32_t*)(uint32_t)(uintptr_t)(const void*)&Bsm[buf][lof[it]],
          16, 0, 0);
    }
  };

  int nk = K >> 5;                 // all K used are multiples of 32, nk >= 8
  stage(0, 0);
  stage(1, 32);

  int bc = 0;                      // compute buffer for iteration t (= t % 3)
  for (int t = 0; t < nk; ++t) {
    __builtin_amdgcn_sched_barrier(0);
    if (t + 1 < nk) {
      asm volatile("s_waitcnt vmcnt(4)" ::: "memory");
    } else {
      asm volatile("s_waitcnt vmcnt(0)" ::: "memory");
    }
    __builtin_amdgcn_s_barrier();
    __builtin_amdgcn_sched_barrier(0);
    if (t + 2 < nk) {
      int bsg = bc - 1; if (bsg < 0) bsg += 3;   // (t+2)%3 == (t-1)%3
      stage(bsg, (t + 2) * 32);
    }
    v8s af[4], bfr[4];
#pragma unroll
    for (int i = 0; i < 4; i++) af[i] = *(const v8s*)&Asm[bc][(wm * 64 + i * 16 + l16) * 32 + sw];
#pragma unroll
    for (int j = 0; j < 4; j++) bfr[j] = *(const v8s*)&Bsm[bc][(wn * 64 + j * 16 + l16) * 32 + sw];
#pragma unroll
    for (int i = 0; i < 4; i++)
#pragma unroll
      for (int j = 0; j < 4; j++)
        acc[i][j] = __builtin_amdgcn_mfma_f32_16x16x32_bf16(af[i], bfr[j], acc[i][j], 0, 0, 0);
    bc++; if (bc == 3) bc = 0;
  }

  float scale = (gidx >= 0) ? gw[gidx] : 1.0f;

  // ---- vectorized epilogue via per-wave LDS transpose ----
  __syncthreads();   // all waves done with Asm/Bsm before scratch reuse
  char* sbase = ((wave < 2) ? (char*)Asm : (char*)Bsm) + (wave & 1) * 12288;

  if (mode != 2) {
    ushort* S16 = (ushort*)sbase;
#pragma unroll
    for (int i = 0; i < 4; i++) {
#pragma unroll
      for (int j = 0; j < 4; j++) {
        int gc = n0 + wn * 64 + j * 16 + l16;
#pragma unroll
        for (int r = 0; r < 4; r++) {
          float v = acc[i][j][r];
          if (mode == 1) {
            float z = v + bias_u[gc];
            v = scale * fast_gelu(z);
          }
          __hip_bfloat16 hb = __float2bfloat16(v);
          S16[(i * 16 + quad * 4 + r) * 72 + j * 16 + l16] = *(const ushort*)&hb;
        }
      }
    }
    asm volatile("s_waitcnt lgkmcnt(0)" ::: "memory");
#pragma unroll
    for (int rr = 0; rr < 8; rr++) {
      int row = rr * 8 + (lane >> 3);
      int col0 = (lane & 7) * 8;
      int gr = m0 + wm * 64 + row;
      v8s val = *(const v8s*)&S16[row * 72 + col0];
      if (gr < M) {
        size_t go = (size_t)gr * ldo + (n0 + wn * 64 + col0);
        if (mode == 1 && addin) {
          v8s av = *(const v8s*)&((const ushort*)addin)[go];
#pragma unroll
          for (int e = 0; e < 8; e++) {
            float fv = __uint_as_float(((uint)(ushort)val[e]) << 16);
            float fa = __uint_as_float(((uint)(ushort)av[e]) << 16);
            __hip_bfloat16 hr = __float2bfloat16(fv + fa);
            val[e] = *(const short*)&hr;
          }
        }
        *(v8s*)&((ushort*)out_u)[go] = val;
      }
    }
  } else {
    float* S32 = (float*)sbase;
#pragma unroll
    for (int h = 0; h < 2; h++) {
      if (h) asm volatile("s_waitcnt lgkmcnt(0)" ::: "memory");  // WAR vs h=0 reads
#pragma unroll
      for (int i = 0; i < 4; i++) {
#pragma unroll
        for (int jj = 0; jj < 2; jj++) {
          int j = h * 2 + jj;
          int gc = n0 + wn * 64 + j * 16 + l16;
#pragma unroll
          for (int r = 0; r < 4; r++)
            S32[(i * 16 + quad * 4 + r) * 36 + jj * 16 + l16] = acc[i][j][r] + bias_u[gc];
        }
      }
      asm volatile("s_waitcnt lgkmcnt(0)" ::: "memory");
#pragma unroll
      for (int rr = 0; rr < 8; rr++) {
        int row = rr * 8 + (lane >> 3);
        int c0 = (lane & 7) * 4;
        int gr = m0 + wm * 64 + row;
        v4f v = *(const v4f*)&S32[row * 36 + c0];
        if (gr < M) {
          int gc0 = n0 + wn * 64 + h * 32 + c0;
          v4f rv = *(const v4f*)&resid_u[(size_t)gr * ldr + gc0];
          v4f sres = v + rv;
          *(v4f*)&((float*)out_u)[(size_t)gr * ldo + gc0] = sres;
        }
      }
    }
  }
}

// ---------------- merged FC1 (large + fused small), 128x64 tile ----------------
// grid (48,130): post-swizzle row-tile mt >= 65 -> small rows (A + B2ROWS):
// one K=768 pass with accumulator snapshots at t==8 (k<256) / t==12 (k<384),
// emits out0=gw0*gelu, outB=+gw1-part, outC=+gw2-part. mt < 65 -> large rows:
// plain gelu(acc+bias) -> outL only. 64x32 per-wave tile; LDS 36KB; staging
// 3 loads/tile -> counted vmcnt(3) depth-2 prefetch.
__global__ __launch_bounds__(256) void fc1m_k(
    const __hip_bfloat16* __restrict__ A, int lda,
    const __hip_bfloat16* __restrict__ Bt, int ldb,
    int M, int K,
    const float* __restrict__ bias,
    const float* __restrict__ gw,
    __hip_bfloat16* __restrict__ outL,
    __hip_bfloat16* __restrict__ out0,
    __hip_bfloat16* __restrict__ outB,
    __hip_bfloat16* __restrict__ outC,
    int ldo) {
  __shared__ __attribute__((aligned(16))) short As2[3][128 * 32];
  __shared__ __attribute__((aligned(16))) short Bs2[3][64 * 32];
  int tid = threadIdx.x, lane = tid & 63, wave = tid >> 6;
  int wm = wave >> 1, wn = wave & 1;
  int l16 = lane & 15, quad = lane >> 4;

  int gx = gridDim.x;                       // 48
  int nwg = gx * gridDim.y;
  int bid = blockIdx.y * gx + blockIdx.x;
  int q8 = nwg >> 3, r8 = nwg & 7;
  int xcd = bid & 7, lid = bid >> 3;
  int nb = (xcd < r8 ? xcd * (q8 + 1) : r8 * (q8 + 1) + (xcd - r8) * q8) + lid;
  int mt = nb / gx;
  bool sm = (mt >= 65);
  int m0 = (sm ? mt - 65 : mt) * 128;
  int n0 = (nb % gx) * 64;

  int sw = (quad ^ ((l16 >> 1) & 3)) * 8;
  int r4 = lane >> 2;
  int qs = (lane & 3) ^ ((r4 >> 1) & 3);

  const ushort* Au = (const ushort*)A + (sm ? (size_t)B2ROWS * lda : 0);
  const ushort* Bu = (const ushort*)Bt;
  const ushort* agp[2];
#pragma unroll
  for (int it = 0; it < 2; it++) {
    int gr = m0 + wave * 16 + it * 64 + r4; if (gr > M - 1) gr = M - 1;
    agp[it] = Au + (size_t)gr * lda + qs * 8;
  }
  const ushort* bgp = Bu + (size_t)(n0 + wave * 16 + r4) * ldb + qs * 8;

  v4f acc[4][2];
#pragma unroll
  for (int i = 0; i < 4; i++)
#pragma unroll
    for (int j = 0; j < 2; j++) acc[i][j] = (v4f){0.f, 0.f, 0.f, 0.f};

  float gw0 = gw[0], gw1 = gw[1], gw2 = gw[2];
  float bias2r[2];
#pragma unroll
  for (int j = 0; j < 2; j++) bias2r[j] = bias[n0 + wn * 32 + j * 16 + l16];

  uint g1p[4][2][2], g2p[4][2][2];

  auto snap = [&](uint (&gp)[4][2][2], float gwX) {
#pragma unroll
    for (int i = 0; i < 4; i++)
#pragma unroll
      for (int j = 0; j < 2; j++)
#pragma unroll
        for (int p = 0; p < 2; p++) {
          float v0 = gwX * fast_gelu(acc[i][j][2 * p] + bias2r[j]);
          float v1 = gwX * fast_gelu(acc[i][j][2 * p + 1] + bias2r[j]);
          __hip_bfloat16 h0 = __float2bfloat16(v0);
          __hip_bfloat16 h1 = __float2bfloat16(v1);
          gp[i][j][p] = ((uint)*(const ushort*)&h1 << 16) | (uint)*(const ushort*)&h0;
        }
  };

  auto stage = [&](int buf, int ko) {
#pragma unroll
    for (int it = 0; it < 2; it++) {
      __builtin_amdgcn_global_load_lds(
          (const __attribute__((address_space(1))) uint32_t*)(uintptr_t)(const void*)(agp[it] + ko),
          (__attribute__((address_space(3))) uint32_t*)(uint32_t)(uintptr_t)(const void*)&As2[buf][(wave * 16 + it * 64) * 32],
          16, 0, 0);
    }
    __builtin_amdgcn_global_load_lds(
        (const __attribute__((address_space(1))) uint32_t*)(uintptr_t)(const void*)(bgp + ko),
        (__attribute__((address_space(3))) uint32_t*)(uint32_t)(uintptr_t)(const void*)&Bs2[buf][(wave * 16) * 32],
        16, 0, 0);
  };

  int nk = K >> 5;
  stage(0, 0);
  stage(1, 32);

  int bc = 0;
  for (int t = 0; t < nk; ++t) {
    if (sm) {
      if (t == 8)  snap(g2p, gw2);   // k < 256 prefix
      if (t == 12) snap(g1p, gw1);   // k < 384 prefix
    }
    __builtin_amdgcn_sched_barrier(0);
    if (t + 1 < nk) {
      asm volatile("s_waitcnt vmcnt(3)" ::: "memory");
    } else {
      asm volatile("s_waitcnt vmcnt(0)" ::: "memory");
    }
    __builtin_amdgcn_s_barrier();
    __builtin_amdgcn_sched_barrier(0);
    if (t + 2 < nk) {
      int bsg = bc - 1; if (bsg < 0) bsg += 3;
      stage(bsg, (t + 2) * 32);
    }
    v8s af[4], bfr[2];
#pragma unroll
    for (int i = 0; i < 4; i++) af[i] = *(const v8s*)&As2[bc][(wm * 64 + i * 16 + l16) * 32 + sw];
#pragma unroll
    for (int j = 0; j < 2; j++) bfr[j] = *(const v8s*)&Bs2[bc][(wn * 32 + j * 16 + l16) * 32 + sw];
#pragma unroll
    for (int i = 0; i < 4; i++)
#pragma unroll
      for (int j = 0; j < 2; j++)
        acc[i][j] = __builtin_amdgcn_mfma_f32_16x16x32_bf16(af[i], bfr[j], acc[i][j], 0, 0, 0);
    bc++; if (bc == 3) bc = 0;
  }

  // ---- epilogue ----
  float s0 = sm ? gw0 : 1.0f;
#pragma unroll
  for (int i = 0; i < 4; i++)
#pragma unroll
    for (int j = 0; j < 2; j++)
#pragma unroll
      for (int r = 0; r < 4; r++)
        acc[i][j][r] = s0 * fast_gelu(acc[i][j][r] + bias2r[j]);

  __syncthreads();   // all waves done with As2/Bs2 before scratch reuse
  ushort* S = (ushort*)As2 + wave * 2560;   // 64 rows x 40 ushorts per wave (5120 B)

  auto flush = [&](void* dst) {
    asm volatile("s_waitcnt lgkmcnt(0)" ::: "memory");  // WAR vs prior reads
#pragma unroll
    for (int i = 0; i < 4; i++)
#pragma unroll
      for (int j = 0; j < 2; j++)
#pragma unroll
        for (int r = 0; r < 4; r++) {
          __hip_bfloat16 hb = __float2bfloat16(acc[i][j][r]);
          S[(i * 16 + quad * 4 + r) * 40 + j * 16 + l16] = *(const ushort*)&hb;
        }
    asm volatile("s_waitcnt lgkmcnt(0)" ::: "memory");
#pragma unroll
    for (int rr = 0; rr < 8; rr++) {
      int row = rr * 8 + (lane >> 3);
      int col0 = (lane & 7) * 4;
      int gr = m0 + wm * 64 + row;
      v4s val = *(const v4s*)&S[row * 40 + col0];
      if (gr < M)
        *(v4s*)&((ushort*)dst)[(size_t)gr * ldo + (n0 + wn * 32 + col0)] = val;
    }
  };

  if (!sm) {
    flush(outL);                                 // large: plain gelu
    return;
  }
  flush(out0);                                   // g0
#pragma unroll
  for (int i = 0; i < 4; i++)
#pragma unroll
    for (int j = 0; j < 2; j++)
#pragma unroll
      for (int p = 0; p < 2; p++) {
        uint u = g1p[i][j][p];
        acc[i][j][2 * p]     += __uint_as_float(u << 16);
        acc[i][j][2 * p + 1] += __uint_as_float(u & 0xffff0000u);
      }
  flush(outB);                                   // g0 + g1
#pragma unroll
  for (int i = 0; i < 4; i++)
#pragma unroll
    for (int j = 0; j < 2; j++)
#pragma unroll
      for (int p = 0; p < 2; p++) {
        uint u = g2p[i][j][p];
        acc[i][j][2 * p]     += __uint_as_float(u << 16);
        acc[i][j][2 * p + 1] += __uint_as_float(u & 0xffff0000u);
      }
  flush(outC);                                   // g0 + g1 + g2
}

// ---------------- fused small-FC1 standalone (fallback path) ----------------
__global__ __launch_bounds__(256) void fc1f_k(
    const __hip_bfloat16* __restrict__ A, int lda,
    const __hip_bfloat16* __restrict__ Bt, int ldb,
    int M, int K,
    const float* __restrict__ bias,
    const float* __restrict__ gw,
    void* __restrict__ out, int ldo,
    __hip_bfloat16* __restrict__ outB,
    __hip_bfloat16* __restrict__ outC) {
  // identical to fc1m_k with sm always true and a (48,65) grid
  __shared__ __attribute__((aligned(16))) short As2[3][128 * 32];
  __shared__ __attribute__((aligned(16))) short Bs2[3][64 * 32];
  int tid = threadIdx.x, lane = tid & 63, wave = tid >> 6;
  int wm = wave >> 1, wn = wave & 1;
  int l16 = lane & 15, quad = lane >> 4;

  int gx = gridDim.x;
  int nwg = gx * gridDim.y;
  int bid = blockIdx.y * gx + blockIdx.x;
  int q8 = nwg >> 3, r8 = nwg & 7;
  int xcd = bid & 7, lid = bid >> 3;
  int nb = (xcd < r8 ? xcd * (q8 + 1) : r8 * (q8 + 1) + (xcd - r8) * q8) + lid;
  int m0 = (nb / gx) * 128, n0 = (nb % gx) * 64;

  int sw = (quad ^ ((l16 >> 1) & 3)) * 8;
  int r4 = lane >> 2;
  int qs = (lane & 3) ^ ((r4 >> 1) & 3);

  const ushort* Au = (const ushort*)A;
  const ushort* Bu = (const ushort*)Bt;
  const ushort* agp[2];
#pragma unroll
  for (int it = 0; it < 2; it++) {
    int gr = m0 + wave * 16 + it * 64 + r4; if (gr > M - 1) gr = M - 1;
    agp[it] = Au + (size_t)gr * lda + qs * 8;
  }
  const ushort* bgp = Bu + (size_t)(n0 + wave * 16 + r4) * ldb + qs * 8;

  v4f acc[4][2];
#pragma unroll
  for (int i = 0; i < 4; i++)
#pragma unroll
    for (int j = 0; j < 2; j++) acc[i][j] = (v4f){0.f, 0.f, 0.f, 0.f};

  float gw0 = gw[0], gw1 = gw[1], gw2 = gw[2];
  float bias2r[2];
#pragma unroll
  for (int j = 0; j < 2; j++) bias2r[j] = bias[n0 + wn * 32 + j * 16 + l16];

  uint g1p[4][2][2], g2p[4][2][2];

  auto snap = [&](uint (&gp)[4][2][2], float gwX) {
#pragma unroll
    for (int i = 0; i < 4; i++)
#pragma unroll
      for (int j = 0; j < 2; j++)
#pragma unroll
        for (int p = 0; p < 2; p++) {
          float v0 = gwX * fast_gelu(acc[i][j][2 * p] + bias2r[j]);
          float v1 = gwX * fast_gelu(acc[i][j][2 * p + 1] + bias2r[j]);
          __hip_bfloat16 h0 = __float2bfloat16(v0);
          __hip_bfloat16 h1 = __float2bfloat16(v1);
          gp[i][j][p] = ((uint)*(const ushort*)&h1 << 16) | (uint)*(const ushort*)&h0;
        }
  };

  auto stage = [&](int buf, int ko) {
#pragma unroll
    for (int it = 0; it < 2; it++) {
      __builtin_amdgcn_global_load_lds(
          (const __attribute__((address_space(1))) uint32_t*)(uintptr_t)(const void*)(agp[it] + ko),
          (__attribute__((address_space(3))) uint32_t*)(uint32_t)(uintptr_t)(const void*)&As2[buf][(wave * 16 + it * 64) * 32],
          16, 0, 0);
    }
    __builtin_amdgcn_global_load_lds(
        (const __attribute__((address_space(1))) uint32_t*)(uintptr_t)(const void*)(bgp + ko),
        (__attribute__((address_space(3))) uint32_t*)(uint32_t)(uintptr_t)(const void*)&Bs2[buf][(wave * 16) * 32],
        16, 0, 0);
  };

  int nk = K >> 5;
  stage(0, 0);
  stage(1, 32);

  int bc = 0;
  for (int t = 0; t < nk; ++t) {
    if (t == 8)  snap(g2p, gw2);
    if (t == 12) snap(g1p, gw1);
    __builtin_amdgcn_sched_barrier(0);
    if (t + 1 < nk) {
      asm volatile("s_waitcnt vmcnt(3)" ::: "memory");
    } else {
      asm volatile("s_waitcnt vmcnt(0)" ::: "memory");
    }
    __builtin_amdgcn_s_barrier();
    __builtin_amdgcn_sched_barrier(0);
    if (t + 2 < nk) {
      int bsg = bc - 1; if (bsg < 0) bsg += 3;
      stage(bsg, (t + 2) * 32);
    }
    v8s af[4], bfr[2];
#pragma unroll
    for (int i = 0; i < 4; i++) af[i] = *(const v8s*)&As2[bc][(wm * 64 + i * 16 + l16) * 32 + sw];
#pragma unroll
    for (int j = 0; j < 2; j++) bfr[j] = *(const v8s*)&Bs2[bc][(wn * 32 + j * 16 + l16) * 32 + sw];
#pragma unroll
    for (int i = 0; i < 4; i++)
#pragma unroll
      for (int j = 0; j < 2; j++)
        acc[i][j] = __builtin_amdgcn_mfma_f32_16x16x32_bf16(af[i], bfr[j], acc[i][j], 0, 0, 0);
    bc++; if (bc == 3) bc = 0;
  }

#pragma unroll
  for (int i = 0; i < 4; i++)
#pragma unroll
    for (int j = 0; j < 2; j++)
#pragma unroll
      for (int r = 0; r < 4; r++)
        acc[i][j][r] = gw0 * fast_gelu(acc[i][j][r] + bias2r[j]);

  __syncthreads();
  ushort* S = (ushort*)As2 + wave * 2560;

  auto flush = [&](void* dst) {
    asm volatile("s_waitcnt lgkmcnt(0)" ::: "memory");
#pragma unroll
    for (int i = 0; i < 4; i++)
#pragma unroll
      for (int j = 0; j < 2; j++)
#pragma unroll
        for (int r = 0; r < 4; r++) {
          __hip_bfloat16 hb = __float2bfloat16(acc[i][j][r]);
          S[(i * 16 + quad * 4 + r) * 40 + j * 16 + l16] = *(const ushort*)&hb;
        }
    asm volatile("s_waitcnt lgkmcnt(0)" ::: "memory");
#pragma unroll
    for (int rr = 0; rr < 8; rr++) {
      int row = rr * 8 + (lane >> 3);
      int col0 = (lane & 7) * 4;
      int gr = m0 + wm * 64 + row;
      v4s val = *(const v4s*)&S[row * 40 + col0];
      if (gr < M)
        *(v4s*)&((ushort*)dst)[(size_t)gr * ldo + (n0 + wn * 32 + col0)] = val;
    }
  };

  flush(out);
#pragma unroll
  for (int i = 0; i < 4; i++)
#pragma unroll
    for (int j = 0; j < 2; j++)
#pragma unroll
      for (int p = 0; p < 2; p++) {
        uint u = g1p[i][j][p];
        acc[i][j][2 * p]     += __uint_as_float(u << 16);
        acc[i][j][2 * p + 1] += __uint_as_float(u & 0xffff0000u);
      }
  flush(outB);
#pragma unroll
  for (int i = 0; i < 4; i++)
#pragma unroll
    for (int j = 0; j < 2; j++)
#pragma unroll
      for (int p = 0; p < 2; p++) {
        uint u = g2p[i][j][p];
        acc[i][j][2 * p]     += __uint_as_float(u << 16);
        acc[i][j][2 * p + 1] += __uint_as_float(u & 0xffff0000u);
      }
  flush(outC);
}

// ---------------- MFMA flash attention (unchanged) ----------------
__global__ __launch_bounds__(256) void attn_k(const __hip_bfloat16* __restrict__ qkv,
                                              __hip_bfloat16* __restrict__ O) {
  __shared__ ushort Ks[64 * 72];
  __shared__ ushort Vs[64 * 64];
  __shared__ ushort Ps[4][16 * 72];
  int bh = blockIdx.x;
  int b = bh / 12, h = bh % 12;
  size_t base = (size_t)b * 257;
  const ushort* Qg = (const ushort*)qkv;
  int tid = threadIdx.x;
  int w = tid >> 6, lane = tid & 63;
  int l16 = lane & 15, quad = lane >> 4;
  int qrow0 = blockIdx.y * 64 + w * 16;

  v8s aq[2];
  {
    int gr = qrow0 + l16; if (gr > 256) gr = 256;
    const ushort* qp = Qg + (base + gr) * 2304 + h * 64;
    aq[0] = *(const v8s*)(qp + quad * 8);
    aq[1] = *(const v8s*)(qp + 32 + quad * 8);
  }

  float mrow[4], lrow[4];
  v4f o[4];
#pragma unroll
  for (int r = 0; r < 4; r++) { mrow[r] = -1e30f; lrow[r] = 0.f; }
#pragma unroll
  for (int dt = 0; dt < 4; dt++) o[dt] = (v4f){0.f, 0.f, 0.f, 0.f};

  for (int kt = 0; kt < 5; kt++) {
    __syncthreads();
#pragma unroll
    for (int it = 0; it < 2; it++) {
      int ch = tid + it * 256;
      int row = ch >> 3, oct = ch & 7;
      int gk = kt * 64 + row; if (gk > 256) gk = 256;
      *(uint4*)&Ks[row * 72 + oct * 8] =
        *(const uint4*)(Qg + (base + gk) * 2304 + 768 + h * 64 + oct * 8);
    }
#pragma unroll
    for (int it = 0; it < 2; it++) {
      int oct = w + it * 4;
      int gk = kt * 64 + lane; if (gk > 256) gk = 256;
      ushort tmp[8];
      *(uint4*)tmp = *(const uint4*)(Qg + (base + gk) * 2304 + 1536 + h * 64 + oct * 8);
#pragma unroll
      for (int j = 0; j < 8; j++) {
        int d = oct * 8 + j;
        Vs[d * 64 + (((lane >> 3) ^ j) * 8) + (lane & 7)] = tmp[j];
      }
    }
    __syncthreads();

    v4f s[4];
#pragma unroll
    for (int jt = 0; jt < 4; jt++) {
      v8s bk0 = *(const v8s*)&Ks[(jt * 16 + l16) * 72 + quad * 8];
      v8s bk1 = *(const v8s*)&Ks[(jt * 16 + l16) * 72 + 32 + quad * 8];
      v4f acc = (v4f){0.f, 0.f, 0.f, 0.f};
      acc = __builtin_amdgcn_mfma_f32_16x16x32_bf16(aq[0], bk0, acc, 0, 0, 0);
      acc = __builtin_amdgcn_mfma_f32_16x16x32_bf16(aq[1], bk1, acc, 0, 0, 0);
      s[jt] = acc;
    }
#pragma unroll
    for (int jt = 0; jt < 4; jt++) {
      int col = kt * 64 + jt * 16 + l16;
      bool valid = col < 257;
#pragma unroll
      for (int r = 0; r < 4; r++)
        s[jt][r] = valid ? s[jt][r] * 0.125f : -1e30f;
    }
    float mnew[4], alpha[4], psum[4];
#pragma unroll
    for (int r = 0; r < 4; r++) {
      float mx = fmaxf(fmaxf(s[0][r], s[1][r]), fmaxf(s[2][r], s[3][r]));
#pragma unroll
      for (int off = 1; off < 16; off <<= 1) mx = fmaxf(mx, __shfl_xor(mx, off, 64));
      mnew[r] = fmaxf(mrow[r], mx);
      alpha[r] = __expf(mrow[r] - mnew[r]);
      mrow[r] = mnew[r];
      psum[r] = 0.f;
    }
#pragma unroll
    for (int jt = 0; jt < 4; jt++) {
#pragma unroll
      for (int r = 0; r < 4; r++) {
        float p = __expf(s[jt][r] - mnew[r]);
        psum[r] += p;
        __hip_bfloat16 pb = __float2bfloat16(p);
        Ps[w][(quad * 4 + r) * 72 + jt * 16 + l16] = *(ushort*)&pb;
      }
    }
#pragma unroll
    for (int r = 0; r < 4; r++) {
#pragma unroll
      for (int off = 1; off < 16; off <<= 1) psum[r] += __shfl_xor(psum[r], off, 64);
      lrow[r] = lrow[r] * alpha[r] + psum[r];
    }
#pragma unroll
    for (int dt = 0; dt < 4; dt++)
#pragma unroll
      for (int r = 0; r < 4; r++) o[dt][r] *= alpha[r];
    v8s pa0 = *(const v8s*)&Ps[w][l16 * 72 + quad * 8];
    v8s pa1 = *(const v8s*)&Ps[w][l16 * 72 + 32 + quad * 8];
#pragma unroll
    for (int dt = 0; dt < 4; dt++) {
      int d = dt * 16 + l16;
      v8s bv0 = *(const v8s*)&Vs[d * 64 + ((quad ^ (d & 7)) * 8)];
      v8s bv1 = *(const v8s*)&Vs[d * 64 + (((4 + quad) ^ (d & 7)) * 8)];
      o[dt] = __builtin_amdgcn_mfma_f32_16x16x32_bf16(pa0, bv0, o[dt], 0, 0, 0);
      o[dt] = __builtin_amdgcn_mfma_f32_16x16x32_bf16(pa1, bv1, o[dt], 0, 0, 0);
    }
  }
#pragma unroll
  for (int r = 0; r < 4; r++) {
    int gr = qrow0 + quad * 4 + r;
    if (gr < 257) {
      float inv = 1.f / lrow[r];
      __hip_bfloat16* orow = O + (base + gr) * 768 + h * 64;
#pragma unroll
      for (int dt = 0; dt < 4; dt++)
        orow[dt * 16 + l16] = __float2bfloat16(o[dt][r] * inv);
    }
  }
}

extern "C" void kernel_launch(void* const* d_in, const int* in_sizes, int n_in,
                              void* d_out, int out_size, void* d_ws, size_t ws_size,
                              hipStream_t stream) {
  const float* x      = (const float*)d_in[0];
  const float* gw     = (const float*)d_in[1];
  const float* n1l_g  = (const float*)d_in[2];
  const float* n1l_b  = (const float*)d_in[3];
  const float* n1s_g  = (const float*)d_in[4];
  const float* n1s_b  = (const float*)d_in[5];
  const float* w_qkv  = (const float*)d_in[6];
  const float* w_proj = (const float*)d_in[7];
  const float* b_proj = (const float*)d_in[8];
  const float* n2l_g  = (const float*)d_in[9];
  const float* n2l_b  = (const float*)d_in[10];
  const float* n2s_g  = (const float*)d_in[11];
  const float* n2s_b  = (const float*)d_in[12];
  const float* w_fc1  = (const float*)d_in[13];
  const float* b_fc1  = (const float*)d_in[14];
  const float* w_fc2  = (const float*)d_in[15];
  const float* b_fc2  = (const float*)d_in[16];
  float* out = (float*)d_out;

  const size_t REQUIRED = (size_t)(2304*768 + 2*768*768 + 2*3072*768) * 2
                        + 2 * 768 * 4 + 512
                        + (size_t)ROWS * 768 * 2
                        + (size_t)ROWS * 2304 * 2;
  if (ws_size < REQUIRED) return;

  char* ws = (char*)d_ws;
  size_t off = 0;
  auto alloc = [&](size_t bytes) -> void* {
    void* p = ws + off;
    off = (off + bytes + 255) & ~(size_t)255;
    return p;
  };
  __hip_bfloat16* wqkv_t  = (__hip_bfloat16*)alloc((size_t)2304 * 768 * 2);
  __hip_bfloat16* wproj_l = (__hip_bfloat16*)alloc((size_t)768 * 768 * 2);
  __hip_bfloat16* wproj_s = (__hip_bfloat16*)alloc((size_t)768 * 768 * 2);
  __hip_bfloat16* wfc1_t  = (__hip_bfloat16*)alloc((size_t)3072 * 768 * 2);
  __hip_bfloat16* wfc2_t  = (__hip_bfloat16*)alloc((size_t)768 * 3072 * 2);
  float* b_small  = (float*)alloc(768 * 4);
  float* b2_small = (float*)alloc(768 * 4);
  __hip_bfloat16* xn   = (__hip_bfloat16*)alloc((size_t)ROWS * 768 * 2);   // also O after attention
  __hip_bfloat16* qkv  = (__hip_bfloat16*)alloc((size_t)ROWS * 2304 * 2);  // also xn2 + hbuf
  __hip_bfloat16* Obuf = xn;
  __hip_bfloat16* xn2  = qkv;
  __hip_bfloat16* hbuf = qkv + (size_t)ROWS * 768;  // 8224*3072 bf16 exactly

  // optional extra buffers for the fused small-FC1 path
  const size_t HB2 = (size_t)B2ROWS * 3072 * 2;    // 50,528,256 B each
  bool roomy3 = ws_size >= REQUIRED + 3 * HB2 + 1024;
  bool roomy2 = ws_size >= REQUIRED + 2 * HB2 + 512;
  __hip_bfloat16 *outB = nullptr, *outC = nullptr, *g0s = nullptr;
  if (roomy3) {
    outB = (__hip_bfloat16*)alloc(HB2);
    outC = (__hip_bfloat16*)alloc(HB2);
    g0s  = (__hip_bfloat16*)alloc(HB2);
  } else if (roomy2) {
    outB = (__hip_bfloat16*)alloc(HB2);
    outC = (__hip_bfloat16*)alloc(HB2);
  }

  // ---- weight / bias prep ----
  wprep<<<dim3(3, 2304), 256, 0, stream>>>(w_qkv, wqkv_t, 768, 2304, 0, gw);
  wprep<<<dim3(3, 768),  256, 0, stream>>>(w_proj, wproj_l, 768, 768, 0, gw);
  wprep<<<dim3(3, 768),  256, 0, stream>>>(w_proj, wproj_s, 768, 768, 1, gw);
  wprep<<<dim3(3, 3072), 256, 0, stream>>>(w_fc1, wfc1_t, 768, 3072, 0, gw);
  wprep<<<dim3(12, 768), 256, 0, stream>>>(w_fc2, wfc2_t, 3072, 768, 0, gw);
  bias_prep<<<3, 256, 0, stream>>>(b_proj, b_fc2, gw, b_small, b2_small);

  // ---- LN1 ----
  ln_k<<<ROWS / 4, 256, 0, stream>>>(x, xn, n1l_g, n1l_b, n1s_g, n1s_b);

  // ---- QKV (grid: x = n-group, y = m-group) ----
  gemm_k<<<dim3(18, 129), 256, 0, stream>>>(xn, 768, wqkv_t, 768, ROWS, 768,
                                            nullptr, nullptr, 0, gw, -1, nullptr,
                                            qkv, 2304, 0, nullptr, nullptr, nullptr, nullptr);
  // ---- attention (MFMA flash) ----
  attn_k<<<dim3(768, 5), 256, 0, stream>>>(qkv, Obuf);

  // ---- proj + residual for BOTH halves in ONE mode-5 dispatch ----
  gemm_k<<<dim3(6, 130), 256, 0, stream>>>(Obuf, 768, wproj_l, 768, B2ROWS, 768,
                                           b_proj, x, 768, gw, -1, nullptr, out, 768, 5,
                                           wproj_s, nullptr, b_small, nullptr);

  // ---- LN2 on x1 (qkv region reused as xn2 + hbuf) ----
  ln_k<<<ROWS / 4, 256, 0, stream>>>(out, xn2, n2l_g, n2l_b, n2s_g, n2s_b);
  const __hip_bfloat16* xn2s = xn2 + (size_t)B2ROWS * 768;
  float* outs = out + (size_t)B2ROWS * 768;

  if (roomy3) {
    // ---- merged FC1: large rows -> hbuf; small rows -> g0s/outB/outC ----
    fc1m_k<<<dim3(48, 130), 256, 0, stream>>>(xn2, 768, wfc1_t, 768, B2ROWS, 768,
                                              b_fc1, gw, hbuf, g0s, outB, outC, 3072);
    // ---- merged FC2: large half A=hbuf; small half per-n0 select ----
    gemm_k<<<dim3(6, 130), 256, 0, stream>>>(hbuf, 3072, wfc2_t, 3072, B2ROWS, 3072,
                                             b_fc2, out, 768, gw, -1, nullptr, out, 768, 6,
                                             outB, outC, b2_small, g0s);
  } else if (roomy2) {
    // ---- round-5 path ----
    gemm_k<<<dim3(24, 65), 256, 0, stream>>>(xn2, 768, wfc1_t, 768, B2ROWS, 768,
                                             b_fc1, nullptr, 0, gw, -1, nullptr, hbuf, 3072, 1,
                                             nullptr, nullptr, nullptr, nullptr);
    gemm_k<<<dim3(6, 65), 256, 0, stream>>>(hbuf, 3072, wfc2_t, 3072, B2ROWS, 3072,
                                            b_fc2, out, 768, gw, -1, nullptr, out, 768, 2,
                                            nullptr, nullptr, nullptr, nullptr);
    fc1f_k<<<dim3(48, 65), 256, 0, stream>>>(xn2s, 768, wfc1_t, 768, B2ROWS, 768,
                                             b_fc1, gw, hbuf, 3072, outB, outC);
    gemm_k<<<dim3(6, 65), 256, 0, stream>>>(hbuf, 3072, wfc2_t, 3072, B2ROWS, 3072,
                                            b2_small, outs, 768, gw, -1, nullptr, outs, 768, 4,
                                            outB, outC, nullptr, nullptr);
  } else {
    // ---- chain fallback ----
    gemm_k<<<dim3(24, 65), 256, 0, stream>>>(xn2, 768, wfc1_t, 768, B2ROWS, 768,
                                             b_fc1, nullptr, 0, gw, -1, nullptr, hbuf, 3072, 1,
                                             nullptr, nullptr, nullptr, nullptr);
    gemm_k<<<dim3(6, 65), 256, 0, stream>>>(hbuf, 3072, wfc2_t, 3072, B2ROWS, 3072,
                                            b_fc2, out, 768, gw, -1, nullptr, out, 768, 2,
                                            nullptr, nullptr, nullptr, nullptr);
    gemm_k<<<dim3(24, 65), 256, 0, stream>>>(xn2s, 768, wfc1_t, 768, B2ROWS, 768,
                                             b_fc1, nullptr, 0, gw, 0, nullptr, hbuf, 3072, 1,
                                             nullptr, nullptr, nullptr, nullptr);
    gemm_k<<<dim3(3, 65), 256, 0, stream>>>(hbuf, 3072, wfc2_t + (size_t)384 * 3072, 3072, B2ROWS, 3072,
                                            b2_small + 384, outs + 384, 768, gw, -1, nullptr, outs + 384, 768, 2,
                                            nullptr, nullptr, nullptr, nullptr);
    gemm_k<<<dim3(24, 65), 256, 0, stream>>>(xn2s, 768, wfc1_t, 768, B2ROWS, 384,
                                             b_fc1, nullptr, 0, gw, 1, hbuf, hbuf, 3072, 1,
                                             nullptr, nullptr, nullptr, nullptr);
    gemm_k<<<dim3(1, 65), 256, 0, stream>>>(hbuf, 3072, wfc2_t + (size_t)256 * 3072, 3072, B2ROWS, 3072,
                                            b2_small + 256, outs + 256, 768, gw, -1, nullptr, outs + 256, 768, 2,
                                            nullptr, nullptr, nullptr, nullptr);
    gemm_k<<<dim3(24, 65), 256, 0, stream>>>(xn2s, 768, wfc1_t, 768, B2ROWS, 256,
                                             b_fc1, nullptr, 0, gw, 2, hbuf, hbuf, 3072, 1,
                                             nullptr, nullptr, nullptr, nullptr);
    gemm_k<<<dim3(2, 65), 256, 0, stream>>>(hbuf, 3072, wfc2_t, 3072, B2ROWS, 3072,
                                            b2_small, outs, 768, gw, -1, nullptr, outs, 768, 2,
                                            nullptr, nullptr, nullptr, nullptr);
  }
}

// Round 7
// 749.559 us; speedup vs baseline: 1.0118x; 1.0118x over previous
//
#include <hip/hip_runtime.h>
#include <hip/hip_bf16.h>

typedef short v8s __attribute__((ext_vector_type(8)));
typedef short v4s __attribute__((ext_vector_type(4)));
typedef float v4f __attribute__((ext_vector_type(4)));

#define B2ROWS 8224   /* 32*257 */
#define ROWS   16448  /* 64*257 */

// Fast exact-GELU: erf via Abramowitz-Stegun 7.1.26 (|err| <= 1.5e-7, far
// below bf16 ulp). ~14 VALU ops (rcp + v_exp + 5 FMA) vs libm erff.
__device__ __forceinline__ float fast_gelu(float z) {
  float u = z * 0.70710678118654752f;
  float a = fabsf(u);
  float t = __builtin_amdgcn_rcpf(1.0f + 0.3275911f * a);
  float p = t * (0.254829592f + t * (-0.284496736f + t * (1.421413741f +
            t * (-1.453152027f + t * 1.061405429f))));
  float e = __expf(-a * a);
  float erfa = 1.0f - p * e;
  float erfu = copysignf(erfa, u);
  return 0.5f * z * (1.0f + erfu);
}

// ---------------- weight prep: transpose fp32 (K x N) -> bf16 (N x K) ----------------
__global__ __launch_bounds__(256) void wprep(const float* __restrict__ W,
                                             __hip_bfloat16* __restrict__ Wt,
                                             int K, int N, int variant,
                                             const float* __restrict__ gw) {
  int k = blockIdx.x * 256 + threadIdx.x;
  int n = blockIdx.y;
  if (k >= K) return;
  float v = W[(size_t)k * N + n];
  if (variant == 1) {
    int h = k >> 6;  // head index
    float s = gw[0];
    if (h < 6 && n < 384) s += gw[1];
    if (h < 4 && n < 256) s += gw[2];
    v *= s;
  }
  Wt[(size_t)n * K + k] = __float2bfloat16(v);
}

__global__ void bias_prep(const float* __restrict__ bp, const float* __restrict__ b2,
                          const float* __restrict__ gw,
                          float* __restrict__ b_small, float* __restrict__ b2_small) {
  int c = blockIdx.x * 256 + threadIdx.x;
  if (c >= 768) return;
  float s = gw[0] + (c < 384 ? gw[1] : 0.f) + (c < 256 ? gw[2] : 0.f);
  b_small[c] = bp[c] * s;
  b2_small[c] = b2[c] * s;
}

// ---------------- LayerNorm: fp32 in -> bf16 out, one row per wave ----------------
__global__ __launch_bounds__(256) void ln_k(const float* __restrict__ X,
                                            __hip_bfloat16* __restrict__ out,
                                            const float* __restrict__ gl, const float* __restrict__ bl,
                                            const float* __restrict__ gs, const float* __restrict__ bs) {
  int wave = threadIdx.x >> 6, lane = threadIdx.x & 63;
  int row = blockIdx.x * 4 + wave;
  const float* g = (row < B2ROWS) ? gl : gs;
  const float* b = (row < B2ROWS) ? bl : bs;
  const float* xr = X + (size_t)row * 768;
  float v[12]; float s = 0.f, ss = 0.f;
#pragma unroll
  for (int i = 0; i < 12; i++) { v[i] = xr[lane + i * 64]; s += v[i]; ss += v[i] * v[i]; }
#pragma unroll
  for (int o = 32; o > 0; o >>= 1) { s += __shfl_xor(s, o, 64); ss += __shfl_xor(ss, o, 64); }
  float mean = s * (1.0f / 768.0f);
  float var = ss * (1.0f / 768.0f) - mean * mean;
  float rstd = rsqrtf(var + 1e-5f);
  __hip_bfloat16* orow = out + (size_t)row * 768;
#pragma unroll
  for (int i = 0; i < 12; i++) {
    int c = lane + i * 64;
    orow[c] = __float2bfloat16((v[i] - mean) * rstd * g[c] + b[c]);
  }
}

// ---------------- bf16 MFMA GEMM: C(MxN) = A(MxK) * Bt(NxK)^T, 128x128 tile ----------------
// v7 = round-5 body + mode 6 kept from round 6 (FC1 merge reverted).
// Main loop: triple-buffered LDS, depth-2 prefetch, counted vmcnt(4), raw
// s_barrier; per-wave LDS-transpose epilogue; bijective XCD swizzle (m204).
// mode 0: out bf16 = acc
// mode 1: out bf16 = scale*gelu(acc + bias) + (addin ? addin : 0)   (addin may alias out)
// mode 2: out fp32 = acc + bias + resid                             (resid may alias out)
// mode 5: merged proj pair (row-tile >= 65 -> small params), then mode 2
// mode 6: merged large+small FC2 (grid y doubled): row-tile >= 65 -> small
//         branch (per-n0 A-select among aux2/aux1/aux3, bias=bias2,
//         resid/out + B2ROWS rows), else large branch; then mode 2.
__global__ __launch_bounds__(256) void gemm_k(
    const __hip_bfloat16* __restrict__ A, int lda,
    const __hip_bfloat16* __restrict__ Bt, int ldb,
    int M, int K,
    const float* __restrict__ bias,
    const float* __restrict__ resid, int ldr,
    const float* __restrict__ gw, int gidx,
    const __hip_bfloat16* __restrict__ addin,
    void* __restrict__ out, int ldo,
    int mode,
    const __hip_bfloat16* __restrict__ aux1,
    const __hip_bfloat16* __restrict__ aux2,
    const float* __restrict__ bias2,
    const __hip_bfloat16* __restrict__ aux3) {
  __shared__ __attribute__((aligned(16))) short Asm[3][128 * 32];
  __shared__ __attribute__((aligned(16))) short Bsm[3][128 * 32];
  int tid = threadIdx.x;
  int lane = tid & 63;
  int wave = tid >> 6;
  int wm = wave >> 1, wn = wave & 1;
  int l16 = lane & 15, quad = lane >> 4;

  // ---- bijective XCD-chunked swizzle (m204) ----
  int gx = gridDim.x;
  int nwg = gx * gridDim.y;
  int bid = blockIdx.y * gx + blockIdx.x;
  int q8 = nwg >> 3, r8 = nwg & 7;
  int xcd = bid & 7, lid = bid >> 3;
  int nb = (xcd < r8 ? xcd * (q8 + 1) : r8 * (q8 + 1) + (xcd - r8) * q8) + lid;
  int m0 = (nb / gx) * 128, n0 = (nb % gx) * 128;

  int sw = (quad ^ ((l16 >> 1) & 3)) * 8;   // swizzled read chunk offset (shorts)

  // per-mode parameter selection
  const __hip_bfloat16* Ause = A;
  const __hip_bfloat16* Btuse = Bt;
  const float* bias_u = bias;
  const float* resid_u = resid;
  void* out_u = out;
  if (mode == 5) {
    if (m0 >= 8320) {                 // 65 * 128: second (small) half
      m0 -= 8320;
      Ause = A + (size_t)B2ROWS * lda;
      Btuse = aux1;
      bias_u = bias2;
      resid_u = resid + (size_t)B2ROWS * ldr;
      out_u = (void*)((float*)out + (size_t)B2ROWS * ldo);
    }
    mode = 2;
  } else if (mode == 6) {
    if (m0 >= 8320) {                 // small half
      m0 -= 8320;
      if (n0 < 256) Ause = aux2;
      else if (n0 < 384) Ause = aux1;
      else Ause = aux3;
      bias_u = bias2;
      resid_u = resid + (size_t)B2ROWS * ldr;
      out_u = (void*)((float*)out + (size_t)B2ROWS * ldo);
    }
    mode = 2;
  }

  // staging address components (per lane)
  int r4 = lane >> 2;                        // row within 16-row wave chunk
  int qs = (lane & 3) ^ ((r4 >> 1) & 3);     // swizzled SOURCE k-chunk

  const ushort* Au = (const ushort*)Ause;
  const ushort* Bu = (const ushort*)Btuse;

  const ushort* agp[2];
  const ushort* bgp[2];
  int lof[2];
#pragma unroll
  for (int it = 0; it < 2; it++) {
    int rbase = wave * 16 + it * 64;
    int gr = m0 + rbase + r4; if (gr > M - 1) gr = M - 1;
    agp[it] = Au + (size_t)gr * lda + qs * 8;
    int gn = n0 + rbase + r4;                // N always a multiple of 128
    bgp[it] = Bu + (size_t)gn * ldb + qs * 8;
    lof[it] = rbase * 32;
  }

  v4f acc[4][4];
#pragma unroll
  for (int i = 0; i < 4; i++)
#pragma unroll
    for (int j = 0; j < 4; j++) acc[i][j] = (v4f){0.f, 0.f, 0.f, 0.f};

  auto stage = [&](int buf, int ko) {
#pragma unroll
    for (int it = 0; it < 2; it++) {
      __builtin_amdgcn_global_load_lds(
          (const __attribute__((address_space(1))) uint32_t*)(uintptr_t)(const void*)(agp[it] + ko),
          (__attribute__((address_space(3))) uint32_t*)(uint32_t)(uintptr_t)(const void*)&Asm[buf][lof[it]],
          16, 0, 0);
      __builtin_amdgcn_global_load_lds(
          (const __attribute__((address_space(1))) uint32_t*)(uintptr_t)(const void*)(bgp[it] + ko),
          (__attribute__((address_space(3))) uint32_t*)(uint32_t)(uintptr_t)(const void*)&Bsm[buf][lof[it]],
          16, 0, 0);
    }
  };

  int nk = K >> 5;                 // all K used are multiples of 32, nk >= 8
  stage(0, 0);
  stage(1, 32);

  int bc = 0;                      // compute buffer for iteration t (= t % 3)
  for (int t = 0; t < nk; ++t) {
    __builtin_amdgcn_sched_barrier(0);
    if (t + 1 < nk) {
      asm volatile("s_waitcnt vmcnt(4)" ::: "memory");
    } else {
      asm volatile("s_waitcnt vmcnt(0)" ::: "memory");
    }
    __builtin_amdgcn_s_barrier();
    __builtin_amdgcn_sched_barrier(0);
    if (t + 2 < nk) {
      int bsg = bc - 1; if (bsg < 0) bsg += 3;   // (t+2)%3 == (t-1)%3
      stage(bsg, (t + 2) * 32);
    }
    v8s af[4], bfr[4];
#pragma unroll
    for (int i = 0; i < 4; i++) af[i] = *(const v8s*)&Asm[bc][(wm * 64 + i * 16 + l16) * 32 + sw];
#pragma unroll
    for (int j = 0; j < 4; j++) bfr[j] = *(const v8s*)&Bsm[bc][(wn * 64 + j * 16 + l16) * 32 + sw];
#pragma unroll
    for (int i = 0; i < 4; i++)
#pragma unroll
      for (int j = 0; j < 4; j++)
        acc[i][j] = __builtin_amdgcn_mfma_f32_16x16x32_bf16(af[i], bfr[j], acc[i][j], 0, 0, 0);
    bc++; if (bc == 3) bc = 0;
  }

  float scale = (gidx >= 0) ? gw[gidx] : 1.0f;

  // ---- vectorized epilogue via per-wave LDS transpose ----
  __syncthreads();   // all waves done with Asm/Bsm before scratch reuse
  char* sbase = ((wave < 2) ? (char*)Asm : (char*)Bsm) + (wave & 1) * 12288;

  if (mode != 2) {
    ushort* S16 = (ushort*)sbase;
#pragma unroll
    for (int i = 0; i < 4; i++) {
#pragma unroll
      for (int j = 0; j < 4; j++) {
        int gc = n0 + wn * 64 + j * 16 + l16;
#pragma unroll
        for (int r = 0; r < 4; r++) {
          float v = acc[i][j][r];
          if (mode == 1) {
            float z = v + bias_u[gc];
            v = scale * fast_gelu(z);
          }
          __hip_bfloat16 hb = __float2bfloat16(v);
          S16[(i * 16 + quad * 4 + r) * 72 + j * 16 + l16] = *(const ushort*)&hb;
        }
      }
    }
    asm volatile("s_waitcnt lgkmcnt(0)" ::: "memory");
#pragma unroll
    for (int rr = 0; rr < 8; rr++) {
      int row = rr * 8 + (lane >> 3);
      int col0 = (lane & 7) * 8;
      int gr = m0 + wm * 64 + row;
      v8s val = *(const v8s*)&S16[row * 72 + col0];
      if (gr < M) {
        size_t go = (size_t)gr * ldo + (n0 + wn * 64 + col0);
        if (mode == 1 && addin) {
          v8s av = *(const v8s*)&((const ushort*)addin)[go];
#pragma unroll
          for (int e = 0; e < 8; e++) {
            float fv = __uint_as_float(((uint)(ushort)val[e]) << 16);
            float fa = __uint_as_float(((uint)(ushort)av[e]) << 16);
            __hip_bfloat16 hr = __float2bfloat16(fv + fa);
            val[e] = *(const short*)&hr;
          }
        }
        *(v8s*)&((ushort*)out_u)[go] = val;
      }
    }
  } else {
    float* S32 = (float*)sbase;
#pragma unroll
    for (int h = 0; h < 2; h++) {
      if (h) asm volatile("s_waitcnt lgkmcnt(0)" ::: "memory");  // WAR vs h=0 reads
#pragma unroll
      for (int i = 0; i < 4; i++) {
#pragma unroll
        for (int jj = 0; jj < 2; jj++) {
          int j = h * 2 + jj;
          int gc = n0 + wn * 64 + j * 16 + l16;
#pragma unroll
          for (int r = 0; r < 4; r++)
            S32[(i * 16 + quad * 4 + r) * 36 + jj * 16 + l16] = acc[i][j][r] + bias_u[gc];
        }
      }
      asm volatile("s_waitcnt lgkmcnt(0)" ::: "memory");
#pragma unroll
      for (int rr = 0; rr < 8; rr++) {
        int row = rr * 8 + (lane >> 3);
        int c0 = (lane & 7) * 4;
        int gr = m0 + wm * 64 + row;
        v4f v = *(const v4f*)&S32[row * 36 + c0];
        if (gr < M) {
          int gc0 = n0 + wn * 64 + h * 32 + c0;
          v4f rv = *(const v4f*)&resid_u[(size_t)gr * ldr + gc0];
          v4f sres = v + rv;
          *(v4f*)&((float*)out_u)[(size_t)gr * ldo + gc0] = sres;
        }
      }
    }
  }
}

// ---------------- fused small-FC1: 128x64 tile, 3 prefix outputs ----------------
// One K=768 pass; accumulator snapshots at t==8 (k<256) and t==12 (k<384)
// packed to bf16 (16 regs each); epilogue emits out=g0, outB=g0+g1,
// outC=g0+g1+g2. 64x32 per-wave tile; LDS 36KB -> 3 blocks/CU; grid (48,65).
// Staging: 3 loads/tile (2 A + 1 B) -> counted vmcnt(3) depth-2 prefetch.
__global__ __launch_bounds__(256) void fc1f_k(
    const __hip_bfloat16* __restrict__ A, int lda,
    const __hip_bfloat16* __restrict__ Bt, int ldb,
    int M, int K,
    const float* __restrict__ bias,
    const float* __restrict__ gw,
    void* __restrict__ out, int ldo,
    __hip_bfloat16* __restrict__ outB,
    __hip_bfloat16* __restrict__ outC) {
  __shared__ __attribute__((aligned(16))) short As2[3][128 * 32];
  __shared__ __attribute__((aligned(16))) short Bs2[3][64 * 32];
  int tid = threadIdx.x, lane = tid & 63, wave = tid >> 6;
  int wm = wave >> 1, wn = wave & 1;
  int l16 = lane & 15, quad = lane >> 4;

  int gx = gridDim.x;                       // 48
  int nwg = gx * gridDim.y;
  int bid = blockIdx.y * gx + blockIdx.x;
  int q8 = nwg >> 3, r8 = nwg & 7;
  int xcd = bid & 7, lid = bid >> 3;
  int nb = (xcd < r8 ? xcd * (q8 + 1) : r8 * (q8 + 1) + (xcd - r8) * q8) + lid;
  int m0 = (nb / gx) * 128, n0 = (nb % gx) * 64;

  int sw = (quad ^ ((l16 >> 1) & 3)) * 8;
  int r4 = lane >> 2;
  int qs = (lane & 3) ^ ((r4 >> 1) & 3);

  const ushort* Au = (const ushort*)A;
  const ushort* Bu = (const ushort*)Bt;
  const ushort* agp[2];
#pragma unroll
  for (int it = 0; it < 2; it++) {
    int gr = m0 + wave * 16 + it * 64 + r4; if (gr > M - 1) gr = M - 1;
    agp[it] = Au + (size_t)gr * lda + qs * 8;
  }
  const ushort* bgp = Bu + (size_t)(n0 + wave * 16 + r4) * ldb + qs * 8;

  v4f acc[4][2];
#pragma unroll
  for (int i = 0; i < 4; i++)
#pragma unroll
    for (int j = 0; j < 2; j++) acc[i][j] = (v4f){0.f, 0.f, 0.f, 0.f};

  float gw0 = gw[0], gw1 = gw[1], gw2 = gw[2];
  float bias2r[2];
#pragma unroll
  for (int j = 0; j < 2; j++) bias2r[j] = bias[n0 + wn * 32 + j * 16 + l16];

  uint g1p[4][2][2], g2p[4][2][2];

  auto snap = [&](uint (&gp)[4][2][2], float gwX) {
#pragma unroll
    for (int i = 0; i < 4; i++)
#pragma unroll
      for (int j = 0; j < 2; j++)
#pragma unroll
        for (int p = 0; p < 2; p++) {
          float v0 = gwX * fast_gelu(acc[i][j][2 * p] + bias2r[j]);
          float v1 = gwX * fast_gelu(acc[i][j][2 * p + 1] + bias2r[j]);
          __hip_bfloat16 h0 = __float2bfloat16(v0);
          __hip_bfloat16 h1 = __float2bfloat16(v1);
          gp[i][j][p] = ((uint)*(const ushort*)&h1 << 16) | (uint)*(const ushort*)&h0;
        }
  };

  auto stage = [&](int buf, int ko) {
#pragma unroll
    for (int it = 0; it < 2; it++) {
      __builtin_amdgcn_global_load_lds(
          (const __attribute__((address_space(1))) uint32_t*)(uintptr_t)(const void*)(agp[it] + ko),
          (__attribute__((address_space(3))) uint32_t*)(uint32_t)(uintptr_t)(const void*)&As2[buf][(wave * 16 + it * 64) * 32],
          16, 0, 0);
    }
    __builtin_amdgcn_global_load_lds(
        (const __attribute__((address_space(1))) uint32_t*)(uintptr_t)(const void*)(bgp + ko),
        (__attribute__((address_space(3))) uint32_t*)(uint32_t)(uintptr_t)(const void*)&Bs2[buf][(wave * 16) * 32],
        16, 0, 0);
  };

  int nk = K >> 5;
  stage(0, 0);
  stage(1, 32);

  int bc = 0;
  for (int t = 0; t < nk; ++t) {
    if (t == 8)  snap(g2p, gw2);   // k < 256 prefix
    if (t == 12) snap(g1p, gw1);   // k < 384 prefix
    __builtin_amdgcn_sched_barrier(0);
    if (t + 1 < nk) {
      asm volatile("s_waitcnt vmcnt(3)" ::: "memory");
    } else {
      asm volatile("s_waitcnt vmcnt(0)" ::: "memory");
    }
    __builtin_amdgcn_s_barrier();
    __builtin_amdgcn_sched_barrier(0);
    if (t + 2 < nk) {
      int bsg = bc - 1; if (bsg < 0) bsg += 3;
      stage(bsg, (t + 2) * 32);
    }
    v8s af[4], bfr[2];
#pragma unroll
    for (int i = 0; i < 4; i++) af[i] = *(const v8s*)&As2[bc][(wm * 64 + i * 16 + l16) * 32 + sw];
#pragma unroll
    for (int j = 0; j < 2; j++) bfr[j] = *(const v8s*)&Bs2[bc][(wn * 32 + j * 16 + l16) * 32 + sw];
#pragma unroll
    for (int i = 0; i < 4; i++)
#pragma unroll
      for (int j = 0; j < 2; j++)
        acc[i][j] = __builtin_amdgcn_mfma_f32_16x16x32_bf16(af[i], bfr[j], acc[i][j], 0, 0, 0);
    bc++; if (bc == 3) bc = 0;
  }

  // ---- epilogue: g0 in acc; emit g0, g0+g1, g0+g1+g2 ----
#pragma unroll
  for (int i = 0; i < 4; i++)
#pragma unroll
    for (int j = 0; j < 2; j++)
#pragma unroll
      for (int r = 0; r < 4; r++)
        acc[i][j][r] = gw0 * fast_gelu(acc[i][j][r] + bias2r[j]);

  __syncthreads();   // all waves done with As2/Bs2 before scratch reuse
  ushort* S = (ushort*)As2 + wave * 2560;   // 64 rows x 40 ushorts per wave (5120 B)

  auto flush = [&](void* dst) {
    asm volatile("s_waitcnt lgkmcnt(0)" ::: "memory");  // WAR vs prior reads
#pragma unroll
    for (int i = 0; i < 4; i++)
#pragma unroll
      for (int j = 0; j < 2; j++)
#pragma unroll
        for (int r = 0; r < 4; r++) {
          __hip_bfloat16 hb = __float2bfloat16(acc[i][j][r]);
          S[(i * 16 + quad * 4 + r) * 40 + j * 16 + l16] = *(const ushort*)&hb;
        }
    asm volatile("s_waitcnt lgkmcnt(0)" ::: "memory");
#pragma unroll
    for (int rr = 0; rr < 8; rr++) {
      int row = rr * 8 + (lane >> 3);
      int col0 = (lane & 7) * 4;
      int gr = m0 + wm * 64 + row;
      v4s val = *(const v4s*)&S[row * 40 + col0];
      if (gr < M)
        *(v4s*)&((ushort*)dst)[(size_t)gr * ldo + (n0 + wn * 32 + col0)] = val;
    }
  };

  flush(out);                                    // g0
#pragma unroll
  for (int i = 0; i < 4; i++)
#pragma unroll
    for (int j = 0; j < 2; j++)
#pragma unroll
      for (int p = 0; p < 2; p++) {
        uint u = g1p[i][j][p];
        acc[i][j][2 * p]     += __uint_as_float(u << 16);
        acc[i][j][2 * p + 1] += __uint_as_float(u & 0xffff0000u);
      }
  flush(outB);                                   // g0 + g1
#pragma unroll
  for (int i = 0; i < 4; i++)
#pragma unroll
    for (int j = 0; j < 2; j++)
#pragma unroll
      for (int p = 0; p < 2; p++) {
        uint u = g2p[i][j][p];
        acc[i][j][2 * p]     += __uint_as_float(u << 16);
        acc[i][j][2 * p + 1] += __uint_as_float(u & 0xffff0000u);
      }
  flush(outC);                                   // g0 + g1 + g2
}

// ---------------- MFMA flash attention (unchanged) ----------------
__global__ __launch_bounds__(256) void attn_k(const __hip_bfloat16* __restrict__ qkv,
                                              __hip_bfloat16* __restrict__ O) {
  __shared__ ushort Ks[64 * 72];
  __shared__ ushort Vs[64 * 64];
  __shared__ ushort Ps[4][16 * 72];
  int bh = blockIdx.x;
  int b = bh / 12, h = bh % 12;
  size_t base = (size_t)b * 257;
  const ushort* Qg = (const ushort*)qkv;
  int tid = threadIdx.x;
  int w = tid >> 6, lane = tid & 63;
  int l16 = lane & 15, quad = lane >> 4;
  int qrow0 = blockIdx.y * 64 + w * 16;

  v8s aq[2];
  {
    int gr = qrow0 + l16; if (gr > 256) gr = 256;
    const ushort* qp = Qg + (base + gr) * 2304 + h * 64;
    aq[0] = *(const v8s*)(qp + quad * 8);
    aq[1] = *(const v8s*)(qp + 32 + quad * 8);
  }

  float mrow[4], lrow[4];
  v4f o[4];
#pragma unroll
  for (int r = 0; r < 4; r++) { mrow[r] = -1e30f; lrow[r] = 0.f; }
#pragma unroll
  for (int dt = 0; dt < 4; dt++) o[dt] = (v4f){0.f, 0.f, 0.f, 0.f};

  for (int kt = 0; kt < 5; kt++) {
    __syncthreads();
#pragma unroll
    for (int it = 0; it < 2; it++) {
      int ch = tid + it * 256;
      int row = ch >> 3, oct = ch & 7;
      int gk = kt * 64 + row; if (gk > 256) gk = 256;
      *(uint4*)&Ks[row * 72 + oct * 8] =
        *(const uint4*)(Qg + (base + gk) * 2304 + 768 + h * 64 + oct * 8);
    }
#pragma unroll
    for (int it = 0; it < 2; it++) {
      int oct = w + it * 4;
      int gk = kt * 64 + lane; if (gk > 256) gk = 256;
      ushort tmp[8];
      *(uint4*)tmp = *(const uint4*)(Qg + (base + gk) * 2304 + 1536 + h * 64 + oct * 8);
#pragma unroll
      for (int j = 0; j < 8; j++) {
        int d = oct * 8 + j;
        Vs[d * 64 + (((lane >> 3) ^ j) * 8) + (lane & 7)] = tmp[j];
      }
    }
    __syncthreads();

    v4f s[4];
#pragma unroll
    for (int jt = 0; jt < 4; jt++) {
      v8s bk0 = *(const v8s*)&Ks[(jt * 16 + l16) * 72 + quad * 8];
      v8s bk1 = *(const v8s*)&Ks[(jt * 16 + l16) * 72 + 32 + quad * 8];
      v4f acc = (v4f){0.f, 0.f, 0.f, 0.f};
      acc = __builtin_amdgcn_mfma_f32_16x16x32_bf16(aq[0], bk0, acc, 0, 0, 0);
      acc = __builtin_amdgcn_mfma_f32_16x16x32_bf16(aq[1], bk1, acc, 0, 0, 0);
      s[jt] = acc;
    }
#pragma unroll
    for (int jt = 0; jt < 4; jt++) {
      int col = kt * 64 + jt * 16 + l16;
      bool valid = col < 257;
#pragma unroll
      for (int r = 0; r < 4; r++)
        s[jt][r] = valid ? s[jt][r] * 0.125f : -1e30f;
    }
    float mnew[4], alpha[4], psum[4];
#pragma unroll
    for (int r = 0; r < 4; r++) {
      float mx = fmaxf(fmaxf(s[0][r], s[1][r]), fmaxf(s[2][r], s[3][r]));
#pragma unroll
      for (int off = 1; off < 16; off <<= 1) mx = fmaxf(mx, __shfl_xor(mx, off, 64));
      mnew[r] = fmaxf(mrow[r], mx);
      alpha[r] = __expf(mrow[r] - mnew[r]);
      mrow[r] = mnew[r];
      psum[r] = 0.f;
    }
#pragma unroll
    for (int jt = 0; jt < 4; jt++) {
#pragma unroll
      for (int r = 0; r < 4; r++) {
        float p = __expf(s[jt][r] - mnew[r]);
        psum[r] += p;
        __hip_bfloat16 pb = __float2bfloat16(p);
        Ps[w][(quad * 4 + r) * 72 + jt * 16 + l16] = *(ushort*)&pb;
      }
    }
#pragma unroll
    for (int r = 0; r < 4; r++) {
#pragma unroll
      for (int off = 1; off < 16; off <<= 1) psum[r] += __shfl_xor(psum[r], off, 64);
      lrow[r] = lrow[r] * alpha[r] + psum[r];
    }
#pragma unroll
    for (int dt = 0; dt < 4; dt++)
#pragma unroll
      for (int r = 0; r < 4; r++) o[dt][r] *= alpha[r];
    v8s pa0 = *(const v8s*)&Ps[w][l16 * 72 + quad * 8];
    v8s pa1 = *(const v8s*)&Ps[w][l16 * 72 + 32 + quad * 8];
#pragma unroll
    for (int dt = 0; dt < 4; dt++) {
      int d = dt * 16 + l16;
      v8s bv0 = *(const v8s*)&Vs[d * 64 + ((quad ^ (d & 7)) * 8)];
      v8s bv1 = *(const v8s*)&Vs[d * 64 + (((4 + quad) ^ (d & 7)) * 8)];
      o[dt] = __builtin_amdgcn_mfma_f32_16x16x32_bf16(pa0, bv0, o[dt], 0, 0, 0);
      o[dt] = __builtin_amdgcn_mfma_f32_16x16x32_bf16(pa1, bv1, o[dt], 0, 0, 0);
    }
  }
#pragma unroll
  for (int r = 0; r < 4; r++) {
    int gr = qrow0 + quad * 4 + r;
    if (gr < 257) {
      float inv = 1.f / lrow[r];
      __hip_bfloat16* orow = O + (base + gr) * 768 + h * 64;
#pragma unroll
      for (int dt = 0; dt < 4; dt++)
        orow[dt * 16 + l16] = __float2bfloat16(o[dt][r] * inv);
    }
  }
}

extern "C" void kernel_launch(void* const* d_in, const int* in_sizes, int n_in,
                              void* d_out, int out_size, void* d_ws, size_t ws_size,
                              hipStream_t stream) {
  const float* x      = (const float*)d_in[0];
  const float* gw     = (const float*)d_in[1];
  const float* n1l_g  = (const float*)d_in[2];
  const float* n1l_b  = (const float*)d_in[3];
  const float* n1s_g  = (const float*)d_in[4];
  const float* n1s_b  = (const float*)d_in[5];
  const float* w_qkv  = (const float*)d_in[6];
  const float* w_proj = (const float*)d_in[7];
  const float* b_proj = (const float*)d_in[8];
  const float* n2l_g  = (const float*)d_in[9];
  const float* n2l_b  = (const float*)d_in[10];
  const float* n2s_g  = (const float*)d_in[11];
  const float* n2s_b  = (const float*)d_in[12];
  const float* w_fc1  = (const float*)d_in[13];
  const float* b_fc1  = (const float*)d_in[14];
  const float* w_fc2  = (const float*)d_in[15];
  const float* b_fc2  = (const float*)d_in[16];
  float* out = (float*)d_out;

  const size_t REQUIRED = (size_t)(2304*768 + 2*768*768 + 2*3072*768) * 2
                        + 2 * 768 * 4 + 512
                        + (size_t)ROWS * 768 * 2
                        + (size_t)ROWS * 2304 * 2;
  if (ws_size < REQUIRED) return;

  char* ws = (char*)d_ws;
  size_t off = 0;
  auto alloc = [&](size_t bytes) -> void* {
    void* p = ws + off;
    off = (off + bytes + 255) & ~(size_t)255;
    return p;
  };
  __hip_bfloat16* wqkv_t  = (__hip_bfloat16*)alloc((size_t)2304 * 768 * 2);
  __hip_bfloat16* wproj_l = (__hip_bfloat16*)alloc((size_t)768 * 768 * 2);
  __hip_bfloat16* wproj_s = (__hip_bfloat16*)alloc((size_t)768 * 768 * 2);
  __hip_bfloat16* wfc1_t  = (__hip_bfloat16*)alloc((size_t)3072 * 768 * 2);
  __hip_bfloat16* wfc2_t  = (__hip_bfloat16*)alloc((size_t)768 * 3072 * 2);
  float* b_small  = (float*)alloc(768 * 4);
  float* b2_small = (float*)alloc(768 * 4);
  __hip_bfloat16* xn   = (__hip_bfloat16*)alloc((size_t)ROWS * 768 * 2);   // also O after attention
  __hip_bfloat16* qkv  = (__hip_bfloat16*)alloc((size_t)ROWS * 2304 * 2);  // also xn2 + hbuf
  __hip_bfloat16* Obuf = xn;
  __hip_bfloat16* xn2  = qkv;
  __hip_bfloat16* hbuf = qkv + (size_t)ROWS * 768;  // 8224*3072 bf16 exactly

  // optional extra buffers for the fused small-FC1 path
  const size_t HB2 = (size_t)B2ROWS * 3072 * 2;    // 50,528,256 B each
  bool roomy3 = ws_size >= REQUIRED + 3 * HB2 + 1024;
  bool roomy2 = ws_size >= REQUIRED + 2 * HB2 + 512;
  __hip_bfloat16 *outB = nullptr, *outC = nullptr, *g0s = nullptr;
  if (roomy3) {
    outB = (__hip_bfloat16*)alloc(HB2);
    outC = (__hip_bfloat16*)alloc(HB2);
    g0s  = (__hip_bfloat16*)alloc(HB2);
  } else if (roomy2) {
    outB = (__hip_bfloat16*)alloc(HB2);
    outC = (__hip_bfloat16*)alloc(HB2);
  }

  // ---- weight / bias prep ----
  wprep<<<dim3(3, 2304), 256, 0, stream>>>(w_qkv, wqkv_t, 768, 2304, 0, gw);
  wprep<<<dim3(3, 768),  256, 0, stream>>>(w_proj, wproj_l, 768, 768, 0, gw);
  wprep<<<dim3(3, 768),  256, 0, stream>>>(w_proj, wproj_s, 768, 768, 1, gw);
  wprep<<<dim3(3, 3072), 256, 0, stream>>>(w_fc1, wfc1_t, 768, 3072, 0, gw);
  wprep<<<dim3(12, 768), 256, 0, stream>>>(w_fc2, wfc2_t, 3072, 768, 0, gw);
  bias_prep<<<3, 256, 0, stream>>>(b_proj, b_fc2, gw, b_small, b2_small);

  // ---- LN1 ----
  ln_k<<<ROWS / 4, 256, 0, stream>>>(x, xn, n1l_g, n1l_b, n1s_g, n1s_b);

  // ---- QKV (grid: x = n-group, y = m-group) ----
  gemm_k<<<dim3(18, 129), 256, 0, stream>>>(xn, 768, wqkv_t, 768, ROWS, 768,
                                            nullptr, nullptr, 0, gw, -1, nullptr,
                                            qkv, 2304, 0, nullptr, nullptr, nullptr, nullptr);
  // ---- attention (MFMA flash) ----
  attn_k<<<dim3(768, 5), 256, 0, stream>>>(qkv, Obuf);

  // ---- proj + residual for BOTH halves in ONE mode-5 dispatch ----
  gemm_k<<<dim3(6, 130), 256, 0, stream>>>(Obuf, 768, wproj_l, 768, B2ROWS, 768,
                                           b_proj, x, 768, gw, -1, nullptr, out, 768, 5,
                                           wproj_s, nullptr, b_small, nullptr);

  // ---- LN2 on x1 (qkv region reused as xn2 + hbuf) ----
  ln_k<<<ROWS / 4, 256, 0, stream>>>(out, xn2, n2l_g, n2l_b, n2s_g, n2s_b);
  const __hip_bfloat16* xn2s = xn2 + (size_t)B2ROWS * 768;
  float* outs = out + (size_t)B2ROWS * 768;

  if (roomy3) {
    // ---- large FC1 (128x128 tile) -> hbuf ----
    gemm_k<<<dim3(24, 65), 256, 0, stream>>>(xn2, 768, wfc1_t, 768, B2ROWS, 768,
                                             b_fc1, nullptr, 0, gw, -1, nullptr, hbuf, 3072, 1,
                                             nullptr, nullptr, nullptr, nullptr);
    // ---- fused small FC1 (one pass, 3 prefix outputs) ----
    fc1f_k<<<dim3(48, 65), 256, 0, stream>>>(xn2s, 768, wfc1_t, 768, B2ROWS, 768,
                                             b_fc1, gw, g0s, 3072, outB, outC);
    // ---- merged FC2 (mode 6): large half A=hbuf; small half per-n0 select ----
    gemm_k<<<dim3(6, 130), 256, 0, stream>>>(hbuf, 3072, wfc2_t, 3072, B2ROWS, 3072,
                                             b_fc2, out, 768, gw, -1, nullptr, out, 768, 6,
                                             outB, outC, b2_small, g0s);
  } else if (roomy2) {
    // ---- round-5 path ----
    gemm_k<<<dim3(24, 65), 256, 0, stream>>>(xn2, 768, wfc1_t, 768, B2ROWS, 768,
                                             b_fc1, nullptr, 0, gw, -1, nullptr, hbuf, 3072, 1,
                                             nullptr, nullptr, nullptr, nullptr);
    gemm_k<<<dim3(6, 65), 256, 0, stream>>>(hbuf, 3072, wfc2_t, 3072, B2ROWS, 3072,
                                            b_fc2, out, 768, gw, -1, nullptr, out, 768, 2,
                                            nullptr, nullptr, nullptr, nullptr);
    fc1f_k<<<dim3(48, 65), 256, 0, stream>>>(xn2s, 768, wfc1_t, 768, B2ROWS, 768,
                                             b_fc1, gw, hbuf, 3072, outB, outC);
    // small FC2 via mode 6 with large half absent is not available here; use
    // three-buffer select through mode 6's small mapping on a (6,65) grid by
    // passing hbuf as aux3 (cols>=384 -> hbuf = g0).
    gemm_k<<<dim3(6, 65), 256, 0, stream>>>(hbuf, 3072, wfc2_t, 3072, B2ROWS, 3072,
                                            b2_small, outs, 768, gw, -1, nullptr, outs, 768, 2,
                                            nullptr, nullptr, nullptr, nullptr);
  } else {
    // ---- chain fallback ----
    gemm_k<<<dim3(24, 65), 256, 0, stream>>>(xn2, 768, wfc1_t, 768, B2ROWS, 768,
                                             b_fc1, nullptr, 0, gw, -1, nullptr, hbuf, 3072, 1,
                                             nullptr, nullptr, nullptr, nullptr);
    gemm_k<<<dim3(6, 65), 256, 0, stream>>>(hbuf, 3072, wfc2_t, 3072, B2ROWS, 3072,
                                            b_fc2, out, 768, gw, -1, nullptr, out, 768, 2,
                                            nullptr, nullptr, nullptr, nullptr);
    gemm_k<<<dim3(24, 65), 256, 0, stream>>>(xn2s, 768, wfc1_t, 768, B2ROWS, 768,
                                             b_fc1, nullptr, 0, gw, 0, nullptr, hbuf, 3072, 1,
                                             nullptr, nullptr, nullptr, nullptr);
    gemm_k<<<dim3(3, 65), 256, 0, stream>>>(hbuf, 3072, wfc2_t + (size_t)384 * 3072, 3072, B2ROWS, 3072,
                                            b2_small + 384, outs + 384, 768, gw, -1, nullptr, outs + 384, 768, 2,
                                            nullptr, nullptr, nullptr, nullptr);
    gemm_k<<<dim3(24, 65), 256, 0, stream>>>(xn2s, 768, wfc1_t, 768, B2ROWS, 384,
                                             b_fc1, nullptr, 0, gw, 1, hbuf, hbuf, 3072, 1,
                                             nullptr, nullptr, nullptr, nullptr);
    gemm_k<<<dim3(1, 65), 256, 0, stream>>>(hbuf, 3072, wfc2_t + (size_t)256 * 3072, 3072, B2ROWS, 3072,
                                            b2_small + 256, outs + 256, 768, gw, -1, nullptr, outs + 256, 768, 2,
                                            nullptr, nullptr, nullptr, nullptr);
    gemm_k<<<dim3(24, 65), 256, 0, stream>>>(xn2s, 768, wfc1_t, 768, B2ROWS, 256,
                                             b_fc1, nullptr, 0, gw, 2, hbuf, hbuf, 3072, 1,
                                             nullptr, nullptr, nullptr, nullptr);
    gemm_k<<<dim3(2, 65), 256, 0, stream>>>(hbuf, 3072, wfc2_t, 3072, B2ROWS, 3072,
                                            b2_small, outs, 768, gw, -1, nullptr, outs, 768, 2,
                                            nullptr, nullptr, nullptr, nullptr);
  }
}

// Round 8
// 723.343 us; speedup vs baseline: 1.0484x; 1.0362x over previous
//
#include <hip/hip_runtime.h>
#include <hip/hip_bf16.h>

typedef short v8s __attribute__((ext_vector_type(8)));
typedef short v4s __attribute__((ext_vector_type(4)));
typedef float v4f __attribute__((ext_vector_type(4)));

#define B2ROWS 8224   /* 32*257 */
#define ROWS   16448  /* 64*257 */

// Fast exact-GELU: erf via Abramowitz-Stegun 7.1.26 (|err| <= 1.5e-7, far
// below bf16 ulp). ~14 VALU ops (rcp + v_exp + 5 FMA) vs libm erff.
__device__ __forceinline__ float fast_gelu(float z) {
  float u = z * 0.70710678118654752f;
  float a = fabsf(u);
  float t = __builtin_amdgcn_rcpf(1.0f + 0.3275911f * a);
  float p = t * (0.254829592f + t * (-0.284496736f + t * (1.421413741f +
            t * (-1.453152027f + t * 1.061405429f))));
  float e = __expf(-a * a);
  float erfa = 1.0f - p * e;
  float erfu = copysignf(erfa, u);
  return 0.5f * z * (1.0f + erfu);
}

// ---------------- weight prep: transpose fp32 (K x N) -> bf16 (N x K) ----------------
__global__ __launch_bounds__(256) void wprep(const float* __restrict__ W,
                                             __hip_bfloat16* __restrict__ Wt,
                                             int K, int N, int variant,
                                             const float* __restrict__ gw) {
  int k = blockIdx.x * 256 + threadIdx.x;
  int n = blockIdx.y;
  if (k >= K) return;
  float v = W[(size_t)k * N + n];
  if (variant == 1) {
    int h = k >> 6;  // head index
    float s = gw[0];
    if (h < 6 && n < 384) s += gw[1];
    if (h < 4 && n < 256) s += gw[2];
    v *= s;
  }
  Wt[(size_t)n * K + k] = __float2bfloat16(v);
}

__global__ void bias_prep(const float* __restrict__ bp, const float* __restrict__ b2,
                          const float* __restrict__ gw,
                          float* __restrict__ b_small, float* __restrict__ b2_small) {
  int c = blockIdx.x * 256 + threadIdx.x;
  if (c >= 768) return;
  float s = gw[0] + (c < 384 ? gw[1] : 0.f) + (c < 256 ? gw[2] : 0.f);
  b_small[c] = bp[c] * s;
  b2_small[c] = b2[c] * s;
}

// ---------------- LayerNorm: fp32 in -> bf16 out, one row per wave ----------------
__global__ __launch_bounds__(256) void ln_k(const float* __restrict__ X,
                                            __hip_bfloat16* __restrict__ out,
                                            const float* __restrict__ gl, const float* __restrict__ bl,
                                            const float* __restrict__ gs, const float* __restrict__ bs) {
  int wave = threadIdx.x >> 6, lane = threadIdx.x & 63;
  int row = blockIdx.x * 4 + wave;
  const float* g = (row < B2ROWS) ? gl : gs;
  const float* b = (row < B2ROWS) ? bl : bs;
  const float* xr = X + (size_t)row * 768;
  float v[12]; float s = 0.f, ss = 0.f;
#pragma unroll
  for (int i = 0; i < 12; i++) { v[i] = xr[lane + i * 64]; s += v[i]; ss += v[i] * v[i]; }
#pragma unroll
  for (int o = 32; o > 0; o >>= 1) { s += __shfl_xor(s, o, 64); ss += __shfl_xor(ss, o, 64); }
  float mean = s * (1.0f / 768.0f);
  float var = ss * (1.0f / 768.0f) - mean * mean;
  float rstd = rsqrtf(var + 1e-5f);
  __hip_bfloat16* orow = out + (size_t)row * 768;
#pragma unroll
  for (int i = 0; i < 12; i++) {
    int c = lane + i * 64;
    orow[c] = __float2bfloat16((v[i] - mean) * rstd * g[c] + b[c]);
  }
}

// ---------------- bf16 MFMA GEMM: C(MxN) = A(MxK) * Bt(NxK)^T, 128x128 tile ----------------
// v8 = exact round-5 structure (best measured, 726.6us). Merges beyond mode 5
// are reverted: L3-working-set model says a merge only helps when the combined
// working set fits 256MB (proj mode-5: ~130MB, helped; FC2 mode-6: ~300MB,
// thrashed, hurt 173us vs ~150us pair).
// Main loop: triple-buffered LDS, depth-2 prefetch, counted vmcnt(4), raw
// s_barrier; per-wave LDS-transpose epilogue; bijective XCD swizzle (m204).
// mode 0: out bf16 = acc
// mode 1: out bf16 = scale*gelu(acc + bias) + (addin ? addin : 0)   (addin may alias out)
// mode 2: out fp32 = acc + bias + resid                             (resid may alias out)
// mode 4: merged small-FC2: A-select by n0 (<256 -> aux2, <384 -> aux1), then mode 2
// mode 5: merged proj pair: grid y doubled (2x65 tiles); post-swizzle row-tile
//         >= 65 selects the small-branch params (A+B2ROWS rows, Bt=aux1,
//         bias=bias2, resid/out + B2ROWS rows), then mode 2.
__global__ __launch_bounds__(256) void gemm_k(
    const __hip_bfloat16* __restrict__ A, int lda,
    const __hip_bfloat16* __restrict__ Bt, int ldb,
    int M, int K,
    const float* __restrict__ bias,
    const float* __restrict__ resid, int ldr,
    const float* __restrict__ gw, int gidx,
    const __hip_bfloat16* __restrict__ addin,
    void* __restrict__ out, int ldo,
    int mode,
    const __hip_bfloat16* __restrict__ aux1,
    const __hip_bfloat16* __restrict__ aux2,
    const float* __restrict__ bias2) {
  __shared__ __attribute__((aligned(16))) short Asm[3][128 * 32];
  __shared__ __attribute__((aligned(16))) short Bsm[3][128 * 32];
  int tid = threadIdx.x;
  int lane = tid & 63;
  int wave = tid >> 6;
  int wm = wave >> 1, wn = wave & 1;
  int l16 = lane & 15, quad = lane >> 4;

  // ---- bijective XCD-chunked swizzle (m204) ----
  int gx = gridDim.x;
  int nwg = gx * gridDim.y;
  int bid = blockIdx.y * gx + blockIdx.x;
  int q8 = nwg >> 3, r8 = nwg & 7;
  int xcd = bid & 7, lid = bid >> 3;
  int nb = (xcd < r8 ? xcd * (q8 + 1) : r8 * (q8 + 1) + (xcd - r8) * q8) + lid;
  int m0 = (nb / gx) * 128, n0 = (nb % gx) * 128;

  int sw = (quad ^ ((l16 >> 1) & 3)) * 8;   // swizzled read chunk offset (shorts)

  // per-mode parameter selection
  const __hip_bfloat16* Ause = A;
  const __hip_bfloat16* Btuse = Bt;
  const float* bias_u = bias;
  const float* resid_u = resid;
  void* out_u = out;
  if (mode == 4) {
    if (n0 < 256) Ause = aux2;
    else if (n0 < 384) Ause = aux1;
    mode = 2;
  } else if (mode == 5) {
    if (m0 >= 8320) {                 // 65 * 128: second (small) half
      m0 -= 8320;
      Ause = A + (size_t)B2ROWS * lda;
      Btuse = aux1;
      bias_u = bias2;
      resid_u = resid + (size_t)B2ROWS * ldr;
      out_u = (void*)((float*)out + (size_t)B2ROWS * ldo);
    }
    mode = 2;
  }

  // staging address components (per lane)
  int r4 = lane >> 2;                        // row within 16-row wave chunk
  int qs = (lane & 3) ^ ((r4 >> 1) & 3);     // swizzled SOURCE k-chunk

  const ushort* Au = (const ushort*)Ause;
  const ushort* Bu = (const ushort*)Btuse;

  const ushort* agp[2];
  const ushort* bgp[2];
  int lof[2];
#pragma unroll
  for (int it = 0; it < 2; it++) {
    int rbase = wave * 16 + it * 64;
    int gr = m0 + rbase + r4; if (gr > M - 1) gr = M - 1;
    agp[it] = Au + (size_t)gr * lda + qs * 8;
    int gn = n0 + rbase + r4;                // N always a multiple of 128
    bgp[it] = Bu + (size_t)gn * ldb + qs * 8;
    lof[it] = rbase * 32;
  }

  v4f acc[4][4];
#pragma unroll
  for (int i = 0; i < 4; i++)
#pragma unroll
    for (int j = 0; j < 4; j++) acc[i][j] = (v4f){0.f, 0.f, 0.f, 0.f};

  auto stage = [&](int buf, int ko) {
#pragma unroll
    for (int it = 0; it < 2; it++) {
      __builtin_amdgcn_global_load_lds(
          (const __attribute__((address_space(1))) uint32_t*)(uintptr_t)(const void*)(agp[it] + ko),
          (__attribute__((address_space(3))) uint32_t*)(uint32_t)(uintptr_t)(const void*)&Asm[buf][lof[it]],
          16, 0, 0);
      __builtin_amdgcn_global_load_lds(
          (const __attribute__((address_space(1))) uint32_t*)(uintptr_t)(const void*)(bgp[it] + ko),
          (__attribute__((address_space(3))) uint32_t*)(uint32_t)(uintptr_t)(const void*)&Bsm[buf][lof[it]],
          16, 0, 0);
    }
  };

  int nk = K >> 5;                 // all K used are multiples of 32, nk >= 8
  stage(0, 0);
  stage(1, 32);

  int bc = 0;                      // compute buffer for iteration t (= t % 3)
  for (int t = 0; t < nk; ++t) {
    __builtin_amdgcn_sched_barrier(0);
    if (t + 1 < nk) {
      asm volatile("s_waitcnt vmcnt(4)" ::: "memory");
    } else {
      asm volatile("s_waitcnt vmcnt(0)" ::: "memory");
    }
    __builtin_amdgcn_s_barrier();
    __builtin_amdgcn_sched_barrier(0);
    if (t + 2 < nk) {
      int bsg = bc - 1; if (bsg < 0) bsg += 3;   // (t+2)%3 == (t-1)%3
      stage(bsg, (t + 2) * 32);
    }
    v8s af[4], bfr[4];
#pragma unroll
    for (int i = 0; i < 4; i++) af[i] = *(const v8s*)&Asm[bc][(wm * 64 + i * 16 + l16) * 32 + sw];
#pragma unroll
    for (int j = 0; j < 4; j++) bfr[j] = *(const v8s*)&Bsm[bc][(wn * 64 + j * 16 + l16) * 32 + sw];
#pragma unroll
    for (int i = 0; i < 4; i++)
#pragma unroll
      for (int j = 0; j < 4; j++)
        acc[i][j] = __builtin_amdgcn_mfma_f32_16x16x32_bf16(af[i], bfr[j], acc[i][j], 0, 0, 0);
    bc++; if (bc == 3) bc = 0;
  }

  float scale = (gidx >= 0) ? gw[gidx] : 1.0f;

  // ---- vectorized epilogue via per-wave LDS transpose ----
  __syncthreads();   // all waves done with Asm/Bsm before scratch reuse
  char* sbase = ((wave < 2) ? (char*)Asm : (char*)Bsm) + (wave & 1) * 12288;

  if (mode != 2) {
    ushort* S16 = (ushort*)sbase;
#pragma unroll
    for (int i = 0; i < 4; i++) {
#pragma unroll
      for (int j = 0; j < 4; j++) {
        int gc = n0 + wn * 64 + j * 16 + l16;
#pragma unroll
        for (int r = 0; r < 4; r++) {
          float v = acc[i][j][r];
          if (mode == 1) {
            float z = v + bias_u[gc];
            v = scale * fast_gelu(z);
          }
          __hip_bfloat16 hb = __float2bfloat16(v);
          S16[(i * 16 + quad * 4 + r) * 72 + j * 16 + l16] = *(const ushort*)&hb;
        }
      }
    }
    asm volatile("s_waitcnt lgkmcnt(0)" ::: "memory");
#pragma unroll
    for (int rr = 0; rr < 8; rr++) {
      int row = rr * 8 + (lane >> 3);
      int col0 = (lane & 7) * 8;
      int gr = m0 + wm * 64 + row;
      v8s val = *(const v8s*)&S16[row * 72 + col0];
      if (gr < M) {
        size_t go = (size_t)gr * ldo + (n0 + wn * 64 + col0);
        if (mode == 1 && addin) {
          v8s av = *(const v8s*)&((const ushort*)addin)[go];
#pragma unroll
          for (int e = 0; e < 8; e++) {
            float fv = __uint_as_float(((uint)(ushort)val[e]) << 16);
            float fa = __uint_as_float(((uint)(ushort)av[e]) << 16);
            __hip_bfloat16 hr = __float2bfloat16(fv + fa);
            val[e] = *(const short*)&hr;
          }
        }
        *(v8s*)&((ushort*)out_u)[go] = val;
      }
    }
  } else {
    float* S32 = (float*)sbase;
#pragma unroll
    for (int h = 0; h < 2; h++) {
      if (h) asm volatile("s_waitcnt lgkmcnt(0)" ::: "memory");  // WAR vs h=0 reads
#pragma unroll
      for (int i = 0; i < 4; i++) {
#pragma unroll
        for (int jj = 0; jj < 2; jj++) {
          int j = h * 2 + jj;
          int gc = n0 + wn * 64 + j * 16 + l16;
#pragma unroll
          for (int r = 0; r < 4; r++)
            S32[(i * 16 + quad * 4 + r) * 36 + jj * 16 + l16] = acc[i][j][r] + bias_u[gc];
        }
      }
      asm volatile("s_waitcnt lgkmcnt(0)" ::: "memory");
#pragma unroll
      for (int rr = 0; rr < 8; rr++) {
        int row = rr * 8 + (lane >> 3);
        int c0 = (lane & 7) * 4;
        int gr = m0 + wm * 64 + row;
        v4f v = *(const v4f*)&S32[row * 36 + c0];
        if (gr < M) {
          int gc0 = n0 + wn * 64 + h * 32 + c0;
          v4f rv = *(const v4f*)&resid_u[(size_t)gr * ldr + gc0];
          v4f sres = v + rv;
          *(v4f*)&((float*)out_u)[(size_t)gr * ldo + gc0] = sres;
        }
      }
    }
  }
}

// ---------------- fused small-FC1: 128x64 tile, 3 prefix outputs ----------------
// One K=768 pass; accumulator snapshots at t==8 (k<256) and t==12 (k<384)
// packed to bf16 (16 regs each); epilogue emits out=g0, outB=g0+g1,
// outC=g0+g1+g2. 64x32 per-wave tile; LDS 36KB -> 3 blocks/CU; grid (48,65).
// Staging: 3 loads/tile (2 A + 1 B) -> counted vmcnt(3) depth-2 prefetch.
// v8 change: NONTEMPORAL output stores. The 148MB triple write stream was
// evicting this kernel's 17MB A/B read set from L2/L3 (FETCH 126MB vs 17MB
// ideal, round-5 counters). nt-stores stream to memory without allocating.
__global__ __launch_bounds__(256) void fc1f_k(
    const __hip_bfloat16* __restrict__ A, int lda,
    const __hip_bfloat16* __restrict__ Bt, int ldb,
    int M, int K,
    const float* __restrict__ bias,
    const float* __restrict__ gw,
    void* __restrict__ out, int ldo,
    __hip_bfloat16* __restrict__ outB,
    __hip_bfloat16* __restrict__ outC) {
  __shared__ __attribute__((aligned(16))) short As2[3][128 * 32];
  __shared__ __attribute__((aligned(16))) short Bs2[3][64 * 32];
  int tid = threadIdx.x, lane = tid & 63, wave = tid >> 6;
  int wm = wave >> 1, wn = wave & 1;
  int l16 = lane & 15, quad = lane >> 4;

  int gx = gridDim.x;                       // 48
  int nwg = gx * gridDim.y;
  int bid = blockIdx.y * gx + blockIdx.x;
  int q8 = nwg >> 3, r8 = nwg & 7;
  int xcd = bid & 7, lid = bid >> 3;
  int nb = (xcd < r8 ? xcd * (q8 + 1) : r8 * (q8 + 1) + (xcd - r8) * q8) + lid;
  int m0 = (nb / gx) * 128, n0 = (nb % gx) * 64;

  int sw = (quad ^ ((l16 >> 1) & 3)) * 8;
  int r4 = lane >> 2;
  int qs = (lane & 3) ^ ((r4 >> 1) & 3);

  const ushort* Au = (const ushort*)A;
  const ushort* Bu = (const ushort*)Bt;
  const ushort* agp[2];
#pragma unroll
  for (int it = 0; it < 2; it++) {
    int gr = m0 + wave * 16 + it * 64 + r4; if (gr > M - 1) gr = M - 1;
    agp[it] = Au + (size_t)gr * lda + qs * 8;
  }
  const ushort* bgp = Bu + (size_t)(n0 + wave * 16 + r4) * ldb + qs * 8;

  v4f acc[4][2];
#pragma unroll
  for (int i = 0; i < 4; i++)
#pragma unroll
    for (int j = 0; j < 2; j++) acc[i][j] = (v4f){0.f, 0.f, 0.f, 0.f};

  float gw0 = gw[0], gw1 = gw[1], gw2 = gw[2];
  float bias2r[2];
#pragma unroll
  for (int j = 0; j < 2; j++) bias2r[j] = bias[n0 + wn * 32 + j * 16 + l16];

  uint g1p[4][2][2], g2p[4][2][2];

  auto snap = [&](uint (&gp)[4][2][2], float gwX) {
#pragma unroll
    for (int i = 0; i < 4; i++)
#pragma unroll
      for (int j = 0; j < 2; j++)
#pragma unroll
        for (int p = 0; p < 2; p++) {
          float v0 = gwX * fast_gelu(acc[i][j][2 * p] + bias2r[j]);
          float v1 = gwX * fast_gelu(acc[i][j][2 * p + 1] + bias2r[j]);
          __hip_bfloat16 h0 = __float2bfloat16(v0);
          __hip_bfloat16 h1 = __float2bfloat16(v1);
          gp[i][j][p] = ((uint)*(const ushort*)&h1 << 16) | (uint)*(const ushort*)&h0;
        }
  };

  auto stage = [&](int buf, int ko) {
#pragma unroll
    for (int it = 0; it < 2; it++) {
      __builtin_amdgcn_global_load_lds(
          (const __attribute__((address_space(1))) uint32_t*)(uintptr_t)(const void*)(agp[it] + ko),
          (__attribute__((address_space(3))) uint32_t*)(uint32_t)(uintptr_t)(const void*)&As2[buf][(wave * 16 + it * 64) * 32],
          16, 0, 0);
    }
    __builtin_amdgcn_global_load_lds(
        (const __attribute__((address_space(1))) uint32_t*)(uintptr_t)(const void*)(bgp + ko),
        (__attribute__((address_space(3))) uint32_t*)(uint32_t)(uintptr_t)(const void*)&Bs2[buf][(wave * 16) * 32],
        16, 0, 0);
  };

  int nk = K >> 5;
  stage(0, 0);
  stage(1, 32);

  int bc = 0;
  for (int t = 0; t < nk; ++t) {
    if (t == 8)  snap(g2p, gw2);   // k < 256 prefix
    if (t == 12) snap(g1p, gw1);   // k < 384 prefix
    __builtin_amdgcn_sched_barrier(0);
    if (t + 1 < nk) {
      asm volatile("s_waitcnt vmcnt(3)" ::: "memory");
    } else {
      asm volatile("s_waitcnt vmcnt(0)" ::: "memory");
    }
    __builtin_amdgcn_s_barrier();
    __builtin_amdgcn_sched_barrier(0);
    if (t + 2 < nk) {
      int bsg = bc - 1; if (bsg < 0) bsg += 3;
      stage(bsg, (t + 2) * 32);
    }
    v8s af[4], bfr[2];
#pragma unroll
    for (int i = 0; i < 4; i++) af[i] = *(const v8s*)&As2[bc][(wm * 64 + i * 16 + l16) * 32 + sw];
#pragma unroll
    for (int j = 0; j < 2; j++) bfr[j] = *(const v8s*)&Bs2[bc][(wn * 32 + j * 16 + l16) * 32 + sw];
#pragma unroll
    for (int i = 0; i < 4; i++)
#pragma unroll
      for (int j = 0; j < 2; j++)
        acc[i][j] = __builtin_amdgcn_mfma_f32_16x16x32_bf16(af[i], bfr[j], acc[i][j], 0, 0, 0);
    bc++; if (bc == 3) bc = 0;
  }

  // ---- epilogue: g0 in acc; emit g0, g0+g1, g0+g1+g2 ----
#pragma unroll
  for (int i = 0; i < 4; i++)
#pragma unroll
    for (int j = 0; j < 2; j++)
#pragma unroll
      for (int r = 0; r < 4; r++)
        acc[i][j][r] = gw0 * fast_gelu(acc[i][j][r] + bias2r[j]);

  __syncthreads();   // all waves done with As2/Bs2 before scratch reuse
  ushort* S = (ushort*)As2 + wave * 2560;   // 64 rows x 40 ushorts per wave (5120 B)

  auto flush = [&](void* dst) {
    asm volatile("s_waitcnt lgkmcnt(0)" ::: "memory");  // WAR vs prior reads
#pragma unroll
    for (int i = 0; i < 4; i++)
#pragma unroll
      for (int j = 0; j < 2; j++)
#pragma unroll
        for (int r = 0; r < 4; r++) {
          __hip_bfloat16 hb = __float2bfloat16(acc[i][j][r]);
          S[(i * 16 + quad * 4 + r) * 40 + j * 16 + l16] = *(const ushort*)&hb;
        }
    asm volatile("s_waitcnt lgkmcnt(0)" ::: "memory");
#pragma unroll
    for (int rr = 0; rr < 8; rr++) {
      int row = rr * 8 + (lane >> 3);
      int col0 = (lane & 7) * 4;
      int gr = m0 + wm * 64 + row;
      v4s val = *(const v4s*)&S[row * 40 + col0];
      if (gr < M)
        __builtin_nontemporal_store(
            val, (v4s*)&((ushort*)dst)[(size_t)gr * ldo + (n0 + wn * 32 + col0)]);
    }
  };

  flush(out);                                    // g0
#pragma unroll
  for (int i = 0; i < 4; i++)
#pragma unroll
    for (int j = 0; j < 2; j++)
#pragma unroll
      for (int p = 0; p < 2; p++) {
        uint u = g1p[i][j][p];
        acc[i][j][2 * p]     += __uint_as_float(u << 16);
        acc[i][j][2 * p + 1] += __uint_as_float(u & 0xffff0000u);
      }
  flush(outB);                                   // g0 + g1
#pragma unroll
  for (int i = 0; i < 4; i++)
#pragma unroll
    for (int j = 0; j < 2; j++)
#pragma unroll
      for (int p = 0; p < 2; p++) {
        uint u = g2p[i][j][p];
        acc[i][j][2 * p]     += __uint_as_float(u << 16);
        acc[i][j][2 * p + 1] += __uint_as_float(u & 0xffff0000u);
      }
  flush(outC);                                   // g0 + g1 + g2
}

// ---------------- MFMA flash attention (unchanged) ----------------
__global__ __launch_bounds__(256) void attn_k(const __hip_bfloat16* __restrict__ qkv,
                                              __hip_bfloat16* __restrict__ O) {
  __shared__ ushort Ks[64 * 72];
  __shared__ ushort Vs[64 * 64];
  __shared__ ushort Ps[4][16 * 72];
  int bh = blockIdx.x;
  int b = bh / 12, h = bh % 12;
  size_t base = (size_t)b * 257;
  const ushort* Qg = (const ushort*)qkv;
  int tid = threadIdx.x;
  int w = tid >> 6, lane = tid & 63;
  int l16 = lane & 15, quad = lane >> 4;
  int qrow0 = blockIdx.y * 64 + w * 16;

  v8s aq[2];
  {
    int gr = qrow0 + l16; if (gr > 256) gr = 256;
    const ushort* qp = Qg + (base + gr) * 2304 + h * 64;
    aq[0] = *(const v8s*)(qp + quad * 8);
    aq[1] = *(const v8s*)(qp + 32 + quad * 8);
  }

  float mrow[4], lrow[4];
  v4f o[4];
#pragma unroll
  for (int r = 0; r < 4; r++) { mrow[r] = -1e30f; lrow[r] = 0.f; }
#pragma unroll
  for (int dt = 0; dt < 4; dt++) o[dt] = (v4f){0.f, 0.f, 0.f, 0.f};

  for (int kt = 0; kt < 5; kt++) {
    __syncthreads();
#pragma unroll
    for (int it = 0; it < 2; it++) {
      int ch = tid + it * 256;
      int row = ch >> 3, oct = ch & 7;
      int gk = kt * 64 + row; if (gk > 256) gk = 256;
      *(uint4*)&Ks[row * 72 + oct * 8] =
        *(const uint4*)(Qg + (base + gk) * 2304 + 768 + h * 64 + oct * 8);
    }
#pragma unroll
    for (int it = 0; it < 2; it++) {
      int oct = w + it * 4;
      int gk = kt * 64 + lane; if (gk > 256) gk = 256;
      ushort tmp[8];
      *(uint4*)tmp = *(const uint4*)(Qg + (base + gk) * 2304 + 1536 + h * 64 + oct * 8);
#pragma unroll
      for (int j = 0; j < 8; j++) {
        int d = oct * 8 + j;
        Vs[d * 64 + (((lane >> 3) ^ j) * 8) + (lane & 7)] = tmp[j];
      }
    }
    __syncthreads();

    v4f s[4];
#pragma unroll
    for (int jt = 0; jt < 4; jt++) {
      v8s bk0 = *(const v8s*)&Ks[(jt * 16 + l16) * 72 + quad * 8];
      v8s bk1 = *(const v8s*)&Ks[(jt * 16 + l16) * 72 + 32 + quad * 8];
      v4f acc = (v4f){0.f, 0.f, 0.f, 0.f};
      acc = __builtin_amdgcn_mfma_f32_16x16x32_bf16(aq[0], bk0, acc, 0, 0, 0);
      acc = __builtin_amdgcn_mfma_f32_16x16x32_bf16(aq[1], bk1, acc, 0, 0, 0);
      s[jt] = acc;
    }
#pragma unroll
    for (int jt = 0; jt < 4; jt++) {
      int col = kt * 64 + jt * 16 + l16;
      bool valid = col < 257;
#pragma unroll
      for (int r = 0; r < 4; r++)
        s[jt][r] = valid ? s[jt][r] * 0.125f : -1e30f;
    }
    float mnew[4], alpha[4], psum[4];
#pragma unroll
    for (int r = 0; r < 4; r++) {
      float mx = fmaxf(fmaxf(s[0][r], s[1][r]), fmaxf(s[2][r], s[3][r]));
#pragma unroll
      for (int off = 1; off < 16; off <<= 1) mx = fmaxf(mx, __shfl_xor(mx, off, 64));
      mnew[r] = fmaxf(mrow[r], mx);
      alpha[r] = __expf(mrow[r] - mnew[r]);
      mrow[r] = mnew[r];
      psum[r] = 0.f;
    }
#pragma unroll
    for (int jt = 0; jt < 4; jt++) {
#pragma unroll
      for (int r = 0; r < 4; r++) {
        float p = __expf(s[jt][r] - mnew[r]);
        psum[r] += p;
        __hip_bfloat16 pb = __float2bfloat16(p);
        Ps[w][(quad * 4 + r) * 72 + jt * 16 + l16] = *(ushort*)&pb;
      }
    }
#pragma unroll
    for (int r = 0; r < 4; r++) {
#pragma unroll
      for (int off = 1; off < 16; off <<= 1) psum[r] += __shfl_xor(psum[r], off, 64);
      lrow[r] = lrow[r] * alpha[r] + psum[r];
    }
#pragma unroll
    for (int dt = 0; dt < 4; dt++)
#pragma unroll
      for (int r = 0; r < 4; r++) o[dt][r] *= alpha[r];
    v8s pa0 = *(const v8s*)&Ps[w][l16 * 72 + quad * 8];
    v8s pa1 = *(const v8s*)&Ps[w][l16 * 72 + 32 + quad * 8];
#pragma unroll
    for (int dt = 0; dt < 4; dt++) {
      int d = dt * 16 + l16;
      v8s bv0 = *(const v8s*)&Vs[d * 64 + ((quad ^ (d & 7)) * 8)];
      v8s bv1 = *(const v8s*)&Vs[d * 64 + (((4 + quad) ^ (d & 7)) * 8)];
      o[dt] = __builtin_amdgcn_mfma_f32_16x16x32_bf16(pa0, bv0, o[dt], 0, 0, 0);
      o[dt] = __builtin_amdgcn_mfma_f32_16x16x32_bf16(pa1, bv1, o[dt], 0, 0, 0);
    }
  }
#pragma unroll
  for (int r = 0; r < 4; r++) {
    int gr = qrow0 + quad * 4 + r;
    if (gr < 257) {
      float inv = 1.f / lrow[r];
      __hip_bfloat16* orow = O + (base + gr) * 768 + h * 64;
#pragma unroll
      for (int dt = 0; dt < 4; dt++)
        orow[dt * 16 + l16] = __float2bfloat16(o[dt][r] * inv);
    }
  }
}

extern "C" void kernel_launch(void* const* d_in, const int* in_sizes, int n_in,
                              void* d_out, int out_size, void* d_ws, size_t ws_size,
                              hipStream_t stream) {
  const float* x      = (const float*)d_in[0];
  const float* gw     = (const float*)d_in[1];
  const float* n1l_g  = (const float*)d_in[2];
  const float* n1l_b  = (const float*)d_in[3];
  const float* n1s_g  = (const float*)d_in[4];
  const float* n1s_b  = (const float*)d_in[5];
  const float* w_qkv  = (const float*)d_in[6];
  const float* w_proj = (const float*)d_in[7];
  const float* b_proj = (const float*)d_in[8];
  const float* n2l_g  = (const float*)d_in[9];
  const float* n2l_b  = (const float*)d_in[10];
  const float* n2s_g  = (const float*)d_in[11];
  const float* n2s_b  = (const float*)d_in[12];
  const float* w_fc1  = (const float*)d_in[13];
  const float* b_fc1  = (const float*)d_in[14];
  const float* w_fc2  = (const float*)d_in[15];
  const float* b_fc2  = (const float*)d_in[16];
  float* out = (float*)d_out;

  const size_t REQUIRED = (size_t)(2304*768 + 2*768*768 + 2*3072*768) * 2
                        + 2 * 768 * 4 + 512
                        + (size_t)ROWS * 768 * 2
                        + (size_t)ROWS * 2304 * 2;
  if (ws_size < REQUIRED) return;

  char* ws = (char*)d_ws;
  size_t off = 0;
  auto alloc = [&](size_t bytes) -> void* {
    void* p = ws + off;
    off = (off + bytes + 255) & ~(size_t)255;
    return p;
  };
  __hip_bfloat16* wqkv_t  = (__hip_bfloat16*)alloc((size_t)2304 * 768 * 2);
  __hip_bfloat16* wproj_l = (__hip_bfloat16*)alloc((size_t)768 * 768 * 2);
  __hip_bfloat16* wproj_s = (__hip_bfloat16*)alloc((size_t)768 * 768 * 2);
  __hip_bfloat16* wfc1_t  = (__hip_bfloat16*)alloc((size_t)3072 * 768 * 2);
  __hip_bfloat16* wfc2_t  = (__hip_bfloat16*)alloc((size_t)768 * 3072 * 2);
  float* b_small  = (float*)alloc(768 * 4);
  float* b2_small = (float*)alloc(768 * 4);
  __hip_bfloat16* xn   = (__hip_bfloat16*)alloc((size_t)ROWS * 768 * 2);   // also O after attention
  __hip_bfloat16* qkv  = (__hip_bfloat16*)alloc((size_t)ROWS * 2304 * 2);  // also xn2 + hbuf
  __hip_bfloat16* Obuf = xn;
  __hip_bfloat16* xn2  = qkv;
  __hip_bfloat16* hbuf = qkv + (size_t)ROWS * 768;  // 8224*3072 bf16 exactly

  // optional extra buffers for the fused small-FC1 path
  const size_t HB2 = (size_t)B2ROWS * 3072 * 2;    // 50,528,256 B each
  bool roomy = ws_size >= REQUIRED + 2 * HB2 + 512;
  __hip_bfloat16 *outB = nullptr, *outC = nullptr;
  if (roomy) {
    outB = (__hip_bfloat16*)alloc(HB2);
    outC = (__hip_bfloat16*)alloc(HB2);
  }

  // ---- weight / bias prep ----
  wprep<<<dim3(3, 2304), 256, 0, stream>>>(w_qkv, wqkv_t, 768, 2304, 0, gw);
  wprep<<<dim3(3, 768),  256, 0, stream>>>(w_proj, wproj_l, 768, 768, 0, gw);
  wprep<<<dim3(3, 768),  256, 0, stream>>>(w_proj, wproj_s, 768, 768, 1, gw);
  wprep<<<dim3(3, 3072), 256, 0, stream>>>(w_fc1, wfc1_t, 768, 3072, 0, gw);
  wprep<<<dim3(12, 768), 256, 0, stream>>>(w_fc2, wfc2_t, 3072, 768, 0, gw);
  bias_prep<<<3, 256, 0, stream>>>(b_proj, b_fc2, gw, b_small, b2_small);

  // ---- LN1 ----
  ln_k<<<ROWS / 4, 256, 0, stream>>>(x, xn, n1l_g, n1l_b, n1s_g, n1s_b);

  // ---- QKV (grid: x = n-group, y = m-group) ----
  gemm_k<<<dim3(18, 129), 256, 0, stream>>>(xn, 768, wqkv_t, 768, ROWS, 768,
                                            nullptr, nullptr, 0, gw, -1, nullptr,
                                            qkv, 2304, 0, nullptr, nullptr, nullptr);
  // ---- attention (MFMA flash) ----
  attn_k<<<dim3(768, 5), 256, 0, stream>>>(qkv, Obuf);

  // ---- proj + residual for BOTH halves in ONE mode-5 dispatch ----
  gemm_k<<<dim3(6, 130), 256, 0, stream>>>(Obuf, 768, wproj_l, 768, B2ROWS, 768,
                                           b_proj, x, 768, gw, -1, nullptr, out, 768, 5,
                                           wproj_s, nullptr, b_small);

  // ---- LN2 on x1 (qkv region reused as xn2 + hbuf) ----
  ln_k<<<ROWS / 4, 256, 0, stream>>>(out, xn2, n2l_g, n2l_b, n2s_g, n2s_b);
  const __hip_bfloat16* xn2s = xn2 + (size_t)B2ROWS * 768;
  float* outs = out + (size_t)B2ROWS * 768;

  // ---- large MLP ----
  gemm_k<<<dim3(24, 65), 256, 0, stream>>>(xn2, 768, wfc1_t, 768, B2ROWS, 768,
                                           b_fc1, nullptr, 0, gw, -1, nullptr, hbuf, 3072, 1,
                                           nullptr, nullptr, nullptr);
  gemm_k<<<dim3(6, 65), 256, 0, stream>>>(hbuf, 3072, wfc2_t, 3072, B2ROWS, 3072,
                                          b_fc2, out, 768, gw, -1, nullptr, out, 768, 2,
                                          nullptr, nullptr, nullptr);

  if (roomy) {
    // ---- small MLP, fused: one FC1 pass emits g0 / g0+g1 / g0+g1+g2 ----
    fc1f_k<<<dim3(48, 65), 256, 0, stream>>>(xn2s, 768, wfc1_t, 768, B2ROWS, 768,
                                             b_fc1, gw, hbuf, 3072, outB, outC);
    // merged FC2: per-block A-select (cols<256 -> outC, <384 -> outB, else hbuf)
    gemm_k<<<dim3(6, 65), 256, 0, stream>>>(hbuf, 3072, wfc2_t, 3072, B2ROWS, 3072,
                                            b2_small, outs, 768, gw, -1, nullptr, outs, 768, 4,
                                            outB, outC, nullptr);
  } else {
    // ---- small MLP fallback: prefix chain in hbuf, FC2 per column slab ----
    gemm_k<<<dim3(24, 65), 256, 0, stream>>>(xn2s, 768, wfc1_t, 768, B2ROWS, 768,
                                             b_fc1, nullptr, 0, gw, 0, nullptr, hbuf, 3072, 1,
                                             nullptr, nullptr, nullptr);
    gemm_k<<<dim3(3, 65), 256, 0, stream>>>(hbuf, 3072, wfc2_t + (size_t)384 * 3072, 3072, B2ROWS, 3072,
                                            b2_small + 384, outs + 384, 768, gw, -1, nullptr, outs + 384, 768, 2,
                                            nullptr, nullptr, nullptr);
    gemm_k<<<dim3(24, 65), 256, 0, stream>>>(xn2s, 768, wfc1_t, 768, B2ROWS, 384,
                                             b_fc1, nullptr, 0, gw, 1, hbuf, hbuf, 3072, 1,
                                             nullptr, nullptr, nullptr);
    gemm_k<<<dim3(1, 65), 256, 0, stream>>>(hbuf, 3072, wfc2_t + (size_t)256 * 3072, 3072, B2ROWS, 3072,
                                            b2_small + 256, outs + 256, 768, gw, -1, nullptr, outs + 256, 768, 2,
                                            nullptr, nullptr, nullptr);
    gemm_k<<<dim3(24, 65), 256, 0, stream>>>(xn2s, 768, wfc1_t, 768, B2ROWS, 256,
                                             b_fc1, nullptr, 0, gw, 2, hbuf, hbuf, 3072, 1,
                                             nullptr, nullptr, nullptr);
    gemm_k<<<dim3(2, 65), 256, 0, stream>>>(hbuf, 3072, wfc2_t, 3072, B2ROWS, 3072,
                                            b2_small, outs, 768, gw, -1, nullptr, outs, 768, 2,
                                            nullptr, nullptr, nullptr);
  }
}